// Round 2
// baseline (434.039 us; speedup 1.0000x reference)
//
#include <hip/hip_runtime.h>
#include <stdint.h>

// GCN forward on MI355X.
// Pipeline: CSR build (count/scan/fill) -> split x,W to bf16 hi/lo ->
//   GEMM1 (relu+bias, split epilogue) -> GEMM2 -> conv1 (split epilogue) ->
//   GEMM3 -> conv2 (f32) -> cls GEMV.
// GEMMs use 3-term bf16 split MFMA (hh+hl+lh) ~= fp32 precision at bf16 rate.

typedef __attribute__((ext_vector_type(8))) __bf16 bf16x8;
typedef __attribute__((ext_vector_type(4))) float f32x4;

static __device__ __forceinline__ unsigned short f32_to_bf16(float f) {
  uint32_t u = __float_as_uint(f);
  u += 0x7fffu + ((u >> 16) & 1u);   // RNE (no NaN handling; data is finite)
  return (unsigned short)(u >> 16);
}
static __device__ __forceinline__ float bf16_to_f32(unsigned short h) {
  return __uint_as_float(((uint32_t)h) << 16);
}

__global__ void zero_ints(int* __restrict__ p, int n) {
  int i = blockIdx.x * blockDim.x + threadIdx.x;
  if (i < n) p[i] = 0;
}

// edge_index may arrive as int32 or int64; detect on-device (values < 2^31,
// so an int64 array has every odd dword == 0 little-endian).
__global__ void detect_i64(const unsigned int* __restrict__ ei, int nwords,
                           int* __restrict__ flag) {
  __shared__ int any;
  if (threadIdx.x == 0) any = 0;
  __syncthreads();
  for (int i = 1 + 2 * (int)threadIdx.x; i < nwords; i += 2 * blockDim.x)
    if (ei[i] != 0u) any = 1;
  __syncthreads();
  if (threadIdx.x == 0) *flag = (any == 0) ? 1 : 0;
}

__global__ void count_deg(const int* __restrict__ ei, int E,
                          const int* __restrict__ flag, int* __restrict__ cnt) {
  int e = blockIdx.x * blockDim.x + threadIdx.x;
  int is64 = *flag;
  if (e < E) {
    int d = is64 ? ei[2 * (E + e)] : ei[E + e];
    atomicAdd(&cnt[d], 1);
  }
}

// Exclusive scan of cnt[0..n) -> row_ptr, plus dinv = 1/sqrt(deg+1).
// 256 threads; thread t owns a contiguous chunk of ceil(n/256) elements:
// serial local sum -> 8-step block scan of 256 partials -> serial prefix
// write-back. Far fewer __syncthreads than a full Hillis-Steele over n.
__global__ __launch_bounds__(256) void scan_rowptr(
    const int* __restrict__ cnt, int* __restrict__ row_ptr,
    float* __restrict__ dinv, int n) {
  __shared__ int partial[256];
  int tid = threadIdx.x;
  int per = (n + 255) / 256;
  int lo = tid * per;
  int hi = lo + per; if (hi > n) hi = n;
  int s = 0;
  for (int i = lo; i < hi; ++i) s += cnt[i];
  partial[tid] = s;
  __syncthreads();
  for (int off = 1; off < 256; off <<= 1) {
    int t = (tid >= off) ? partial[tid - off] : 0;
    __syncthreads();
    partial[tid] += t;
    __syncthreads();
  }
  int run = (tid > 0) ? partial[tid - 1] : 0;   // exclusive base of my chunk
  for (int i = lo; i < hi; ++i) {
    int v = cnt[i];
    row_ptr[i] = run;
    dinv[i] = 1.0f / sqrtf((float)(v + 1));     // +1 self-loop
    run += v;
  }
  if (tid == 255) row_ptr[n] = partial[255];
}

__global__ void fill_csr(const int* __restrict__ ei, int E,
                         const int* __restrict__ flag,
                         const int* __restrict__ row_ptr, int* __restrict__ cursor,
                         int* __restrict__ csr_src) {
  int e = blockIdx.x * blockDim.x + threadIdx.x;
  int is64 = *flag;
  if (e < E) {
    int s = is64 ? ei[2 * e] : ei[e];
    int d = is64 ? ei[2 * (E + e)] : ei[E + e];
    int pos = row_ptr[d] + atomicAdd(&cursor[d], 1);
    csr_src[pos] = s;
  }
}

__global__ void split_x(const float4* __restrict__ in, unsigned short* __restrict__ hi,
                        unsigned short* __restrict__ lo, int n4) {
  int i = blockIdx.x * blockDim.x + threadIdx.x;
  if (i >= n4) return;
  float4 v = in[i];
  float vv[4] = {v.x, v.y, v.z, v.w};
  unsigned short hs[4], ls[4];
#pragma unroll
  for (int j = 0; j < 4; ++j) {
    unsigned short h = f32_to_bf16(vv[j]);
    hs[j] = h;
    ls[j] = f32_to_bf16(vv[j] - bf16_to_f32(h));
  }
  ((ushort4*)hi)[i] = make_ushort4(hs[0], hs[1], hs[2], hs[3]);
  ((ushort4*)lo)[i] = make_ushort4(ls[0], ls[1], ls[2], ls[3]);
}

// W [k][n] (row-major 256x256) -> WT_hi/lo [n][k] bf16 split
__global__ void transpose_split(const float* __restrict__ W,
                                unsigned short* __restrict__ Thi,
                                unsigned short* __restrict__ Tlo) {
  int n = blockIdx.x;
  int k = threadIdx.x;
  float v = W[k * 256 + n];
  unsigned short h = f32_to_bf16(v);
  Thi[n * 256 + k] = h;
  Tlo[n * 256 + k] = f32_to_bf16(v - bf16_to_f32(h));
}

// C = A @ B, A [M,256] as bf16 hi/lo, B^T [256,256] as bf16 hi/lo.
// 3-term split: A_hi*B_hi + A_hi*B_lo + A_lo*B_hi (f32 accum) ~ fp32.
// Block: 256 thr = 4 waves; tile 64(M)x128(N); wave w owns rows [m0+16w, +16).
// mfma_f32_16x16x32_bf16 layouts (learn_hip m89/m91-verified):
//   A: lane l holds A[l&15][(l>>4)*8 + j];  B: lane l holds B[(l>>4)*8+j][l&15]
//   D: col = lane&15, row = (lane>>4)*4 + reg
// MODE 0: write f32.  MODE 1: +bias, relu, write bf16 hi/lo split.
template <int MODE>
__global__ __launch_bounds__(256) void gemm_split(
    const unsigned short* __restrict__ Ahi, const unsigned short* __restrict__ Alo,
    const unsigned short* __restrict__ BThi, const unsigned short* __restrict__ BTlo,
    int M, const float* __restrict__ bias, float* __restrict__ outf,
    unsigned short* __restrict__ outhi, unsigned short* __restrict__ outlo) {
  const int K = 256;
  int wid = threadIdx.x >> 6;
  int lane = threadIdx.x & 63;
  int r = lane & 15, g = lane >> 4;
  int m0 = blockIdx.x * 64 + wid * 16;
  int n0 = blockIdx.y * 128;
  int arow = m0 + r;
  if (arow >= M) arow = M - 1;  // clamp; OOB D-rows are masked at store

  const unsigned short* aph = Ahi + arow * K + g * 8;
  const unsigned short* apl = Alo + arow * K + g * 8;
  const unsigned short* bph = BThi + (n0 + r) * K + g * 8;
  const unsigned short* bpl = BTlo + (n0 + r) * K + g * 8;

  f32x4 acc[8] = {};
#pragma unroll
  for (int k0 = 0; k0 < K; k0 += 32) {
    bf16x8 ah = *(const bf16x8*)(aph + k0);
    bf16x8 al = *(const bf16x8*)(apl + k0);
#pragma unroll
    for (int n = 0; n < 8; ++n) {
      bf16x8 bh = *(const bf16x8*)(bph + n * 16 * K + k0);
      bf16x8 bl = *(const bf16x8*)(bpl + n * 16 * K + k0);
      acc[n] = __builtin_amdgcn_mfma_f32_16x16x32_bf16(ah, bh, acc[n], 0, 0, 0);
      acc[n] = __builtin_amdgcn_mfma_f32_16x16x32_bf16(ah, bl, acc[n], 0, 0, 0);
      acc[n] = __builtin_amdgcn_mfma_f32_16x16x32_bf16(al, bh, acc[n], 0, 0, 0);
    }
  }
#pragma unroll
  for (int n = 0; n < 8; ++n) {
    int col = n0 + n * 16 + r;
    float bcol = (MODE == 1) ? bias[col] : 0.0f;
#pragma unroll
    for (int i = 0; i < 4; ++i) {
      int row = m0 + g * 4 + i;
      if (row < M) {
        float v = acc[n][i];
        if (MODE == 1) {
          v = fmaxf(v + bcol, 0.0f);
          unsigned short h = f32_to_bf16(v);
          outhi[row * 256 + col] = h;
          outlo[row * 256 + col] = f32_to_bf16(v - bf16_to_f32(h));
        } else {
          outf[row * 256 + col] = v;
        }
      }
    }
  }
}

// out[i] = b + dinv[i] * sum_{e in CSR(i)} dinv[src] * h[src] + dinv[i]^2 * h[i]
// One wave per node; lane handles cols [4*lane, 4*lane+4) as float4 (1KB/row).
// Edge loop unrolled x2: two independent FMA chains to hide L3 gather latency.
// MODE 0: f32 out.  MODE 1: bf16 hi/lo split out (feeds next GEMM).
template <int MODE>
__global__ __launch_bounds__(256) void gcn_conv(
    const float* __restrict__ h, const int* __restrict__ row_ptr,
    const int* __restrict__ csr_src, const float* __restrict__ dinv,
    const float* __restrict__ bias, int n_nodes, float* __restrict__ outf,
    unsigned short* __restrict__ outhi, unsigned short* __restrict__ outlo) {
  int wid = threadIdx.x >> 6, lane = threadIdx.x & 63;
  int node = blockIdx.x * 4 + wid;
  if (node >= n_nodes) return;
  const float4* hp = (const float4*)h;
  float4 a0 = make_float4(0.f, 0.f, 0.f, 0.f);
  float4 a1 = make_float4(0.f, 0.f, 0.f, 0.f);
  int e0 = row_ptr[node], e1 = row_ptr[node + 1];
  int e = e0;
  for (; e + 1 < e1; e += 2) {
    int s0 = csr_src[e], s1 = csr_src[e + 1];
    float d0 = dinv[s0], d1 = dinv[s1];
    float4 v0 = hp[s0 * 64 + lane];
    float4 v1 = hp[s1 * 64 + lane];
    a0.x += d0 * v0.x; a0.y += d0 * v0.y; a0.z += d0 * v0.z; a0.w += d0 * v0.w;
    a1.x += d1 * v1.x; a1.y += d1 * v1.y; a1.z += d1 * v1.z; a1.w += d1 * v1.w;
  }
  if (e < e1) {
    int s0 = csr_src[e];
    float d0 = dinv[s0];
    float4 v0 = hp[s0 * 64 + lane];
    a0.x += d0 * v0.x; a0.y += d0 * v0.y; a0.z += d0 * v0.z; a0.w += d0 * v0.w;
  }
  float di = dinv[node];
  float4 self = hp[node * 64 + lane];
  float4 b4 = ((const float4*)bias)[lane];
  float o[4];
  o[0] = di * (a0.x + a1.x) + di * di * self.x + b4.x;
  o[1] = di * (a0.y + a1.y) + di * di * self.y + b4.y;
  o[2] = di * (a0.z + a1.z) + di * di * self.z + b4.z;
  o[3] = di * (a0.w + a1.w) + di * di * self.w + b4.w;
  if (MODE == 1) {
    unsigned short hs[4], ls[4];
#pragma unroll
    for (int j = 0; j < 4; ++j) {
      unsigned short hh = f32_to_bf16(o[j]);
      hs[j] = hh;
      ls[j] = f32_to_bf16(o[j] - bf16_to_f32(hh));
    }
    int idx = node * 64 + lane;
    ((ushort4*)outhi)[idx] = make_ushort4(hs[0], hs[1], hs[2], hs[3]);
    ((ushort4*)outlo)[idx] = make_ushort4(ls[0], ls[1], ls[2], ls[3]);
  } else {
    ((float4*)outf)[node * 64 + lane] = make_float4(o[0], o[1], o[2], o[3]);
  }
}

// logits = h @ Wcls[256,3] + bcls; wave per node, shuffle-reduce.
__global__ __launch_bounds__(256) void cls_kernel(
    const float* __restrict__ h, const float* __restrict__ Wcls,
    const float* __restrict__ bcls, float* __restrict__ out, int n_nodes) {
  int wid = threadIdx.x >> 6, lane = threadIdx.x & 63;
  int node = blockIdx.x * 4 + wid;
  if (node >= n_nodes) return;
  float4 v = ((const float4*)(h + node * 256))[lane];
  float vv[4] = {v.x, v.y, v.z, v.w};
  float s0 = 0.f, s1 = 0.f, s2 = 0.f;
#pragma unroll
  for (int j = 0; j < 4; ++j) {
    int k = lane * 4 + j;
    s0 += vv[j] * Wcls[k * 3 + 0];
    s1 += vv[j] * Wcls[k * 3 + 1];
    s2 += vv[j] * Wcls[k * 3 + 2];
  }
#pragma unroll
  for (int off = 32; off > 0; off >>= 1) {
    s0 += __shfl_down(s0, off);
    s1 += __shfl_down(s1, off);
    s2 += __shfl_down(s2, off);
  }
  if (lane == 0) {
    out[node * 3 + 0] = s0 + bcls[0];
    out[node * 3 + 1] = s1 + bcls[1];
    out[node * 3 + 2] = s2 + bcls[2];
  }
}

extern "C" void kernel_launch(void* const* d_in, const int* in_sizes, int n_in,
                              void* d_out, int out_size, void* d_ws, size_t ws_size,
                              hipStream_t stream) {
  const float* x = (const float*)d_in[0];
  const int* ei = (const int*)d_in[1];
  const float* W_embed = (const float*)d_in[2];
  const float* b_embed = (const float*)d_in[3];
  const float* W1 = (const float*)d_in[4];
  const float* b1 = (const float*)d_in[5];
  const float* W2 = (const float*)d_in[6];
  const float* b2 = (const float*)d_in[7];
  const float* Wcls = (const float*)d_in[8];
  const float* bcls = (const float*)d_in[9];
  const int N = in_sizes[0] / 256;   // 20000
  const int E = in_sizes[1] / 2;     // 320000

  char* ws = (char*)d_ws;
  size_t off = 0;
  auto alloc = [&](size_t bytes) {
    void* p = ws + off;
    off = (off + bytes + 255) & ~(size_t)255;
    return p;
  };
  int* cnt = (int*)alloc((size_t)N * 4);
  int* cursor = (int*)alloc((size_t)N * 4);
  int* row_ptr = (int*)alloc((size_t)(N + 1) * 4);
  float* dinv = (float*)alloc((size_t)N * 4);
  int* csr_src = (int*)alloc((size_t)E * 4);
  int* flag = (int*)alloc(256);
  unsigned short* WemThi = (unsigned short*)alloc(256 * 256 * 2);
  unsigned short* WemTlo = (unsigned short*)alloc(256 * 256 * 2);
  unsigned short* W1Thi = (unsigned short*)alloc(256 * 256 * 2);
  unsigned short* W1Tlo = (unsigned short*)alloc(256 * 256 * 2);
  unsigned short* W2Thi = (unsigned short*)alloc(256 * 256 * 2);
  unsigned short* W2Tlo = (unsigned short*)alloc(256 * 256 * 2);
  size_t big = (size_t)N * 256;
  // P1: x hi/lo, later reused as h2 hi/lo. P2: h0 hi/lo, later h3 f32. P3: h1 f32, later h4 f32.
  unsigned short* P1hi = (unsigned short*)alloc(big * 4);  // two bf16 planes
  unsigned short* P1lo = P1hi + big;
  unsigned short* P2hi = (unsigned short*)alloc(big * 4);
  unsigned short* P2lo = P2hi + big;
  float* P2f = (float*)P2hi;
  float* P3f = (float*)alloc(big * 4);

  int nz = (int)(((char*)row_ptr - (char*)cnt) / 4);  // cnt + cursor (incl pad)
  zero_ints<<<(nz + 255) / 256, 256, 0, stream>>>(cnt, nz);
  detect_i64<<<1, 256, 0, stream>>>((const unsigned int*)ei, 4096, flag);
  count_deg<<<(E + 255) / 256, 256, 0, stream>>>(ei, E, flag, cnt);
  scan_rowptr<<<1, 256, 0, stream>>>(cnt, row_ptr, dinv, N);
  fill_csr<<<(E + 255) / 256, 256, 0, stream>>>(ei, E, flag, row_ptr, cursor, csr_src);

  split_x<<<(N * 64 + 255) / 256, 256, 0, stream>>>((const float4*)x, P1hi, P1lo, N * 64);
  transpose_split<<<256, 256, 0, stream>>>(W_embed, WemThi, WemTlo);
  transpose_split<<<256, 256, 0, stream>>>(W1, W1Thi, W1Tlo);
  transpose_split<<<256, 256, 0, stream>>>(W2, W2Thi, W2Tlo);

  dim3 gg((N + 63) / 64, 2);
  // h0 = relu(x@We + be)  -> P2 hi/lo
  gemm_split<1><<<gg, 256, 0, stream>>>(P1hi, P1lo, WemThi, WemTlo, N, b_embed,
                                        nullptr, P2hi, P2lo);
  // h1 = h0@W1 -> P3 f32
  gemm_split<0><<<gg, 256, 0, stream>>>(P2hi, P2lo, W1Thi, W1Tlo, N, nullptr,
                                        P3f, nullptr, nullptr);
  // h2 = conv(h1) + b1 -> P1 hi/lo
  gcn_conv<1><<<(N + 3) / 4, 256, 0, stream>>>(P3f, row_ptr, csr_src, dinv, b1, N,
                                               nullptr, P1hi, P1lo);
  // h3 = h2@W2 -> P2 f32
  gemm_split<0><<<gg, 256, 0, stream>>>(P1hi, P1lo, W2Thi, W2Tlo, N, nullptr,
                                        P2f, nullptr, nullptr);
  // h4 = conv(h3) + b2 -> P3 f32
  gcn_conv<0><<<(N + 3) / 4, 256, 0, stream>>>(P2f, row_ptr, csr_src, dinv, b2, N,
                                               P3f, nullptr, nullptr);
  // logits = h4@Wcls + bcls
  cls_kernel<<<(N + 3) / 4, 256, 0, stream>>>(P3f, Wcls, bcls, (float*)d_out, N);
}

// Round 6
// 328.691 us; speedup vs baseline: 1.3205x; 1.3205x over previous
//
#include <hip/hip_runtime.h>
#include <stdint.h>

// GCN forward on MI355X.
// Pipeline: CSR build (count/scan/fill) -> pack x,W into MFMA-fragment-major
//   bf16 hi/lo -> GEMM1 (relu+bias, frag epilogue) -> GEMM2 -> conv1 (frag
//   epilogue) -> GEMM3 -> conv2 (fused classifier -> logits).
// GEMMs: 3-term bf16 split MFMA (hh+hl+lh) ~= fp32 precision at bf16 rate.
//
// R2 lesson (rocprof): direct strided fragment loads = 16 scattered L2
// transactions per instr -> VMEM-issue bound, 58 us/GEMM, MfmaUtil 4.8%.
// Fix: fragment-major storage. Fragment f(tile,k0) = 1KB contiguous; lane l
// reads [base + 16*l] -> every GEMM load is one coalesced 1KB burst.
//
// Fragment-major addressing (mfma_f32_16x16x32_bf16, m89/m91-verified):
//   A-frag: lane = (m&15) + 16*((k>>3)&3), j = k&7
//   elem (m,k) -> short addr = ((m>>4)*8 + (k>>5))*512 + lane*8 + j
//   B-frag identical with n in place of m.
//   D-frag: col = lane&15, row = (lane>>4)*4 + i

typedef __attribute__((ext_vector_type(8))) __bf16 bf16x8;
typedef __attribute__((ext_vector_type(4))) float f32x4;

static __device__ __forceinline__ unsigned short f32_to_bf16(float f) {
  uint32_t u = __float_as_uint(f);
  u += 0x7fffu + ((u >> 16) & 1u);   // RNE (finite data)
  return (unsigned short)(u >> 16);
}
static __device__ __forceinline__ float bf16_to_f32(unsigned short h) {
  return __uint_as_float(((uint32_t)h) << 16);
}
static __device__ __forceinline__ int frag_addr(int m, int k) {
  return (((m >> 4) * 8 + (k >> 5)) << 9) + (((m & 15) + 16 * ((k >> 3) & 3)) << 3) + (k & 7);
}

__global__ void zero_ints(int* __restrict__ p, int n) {
  int i = blockIdx.x * blockDim.x + threadIdx.x;
  if (i < n) p[i] = 0;
}

// edge_index may arrive as int32 or int64; detect on-device (values < 2^31,
// so an int64 array has every odd dword == 0 little-endian).
__global__ void detect_i64(const unsigned int* __restrict__ ei, int nwords,
                           int* __restrict__ flag) {
  __shared__ int any;
  if (threadIdx.x == 0) any = 0;
  __syncthreads();
  for (int i = 1 + 2 * (int)threadIdx.x; i < nwords; i += 2 * blockDim.x)
    if (ei[i] != 0u) any = 1;
  __syncthreads();
  if (threadIdx.x == 0) *flag = (any == 0) ? 1 : 0;
}

__global__ void count_deg(const int* __restrict__ ei, int E,
                          const int* __restrict__ flag, int* __restrict__ cnt) {
  int e = blockIdx.x * blockDim.x + threadIdx.x;
  int is64 = *flag;
  if (e < E) {
    int d = is64 ? ei[2 * (E + e)] : ei[E + e];
    atomicAdd(&cnt[d], 1);
  }
}

// Exclusive scan of cnt -> row_ptr, plus dinv = 1/sqrt(deg+1).
// 256 threads, contiguous chunks; 8-step block scan of partials.
__global__ __launch_bounds__(256) void scan_rowptr(
    const int* __restrict__ cnt, int* __restrict__ row_ptr,
    float* __restrict__ dinv, int n) {
  __shared__ int partial[256];
  int tid = threadIdx.x;
  int per = (n + 255) / 256;
  int lo = tid * per;
  int hi = lo + per; if (hi > n) hi = n;
  int s = 0;
  for (int i = lo; i < hi; ++i) s += cnt[i];
  partial[tid] = s;
  __syncthreads();
  for (int off = 1; off < 256; off <<= 1) {
    int t = (tid >= off) ? partial[tid - off] : 0;
    __syncthreads();
    partial[tid] += t;
    __syncthreads();
  }
  int run = (tid > 0) ? partial[tid - 1] : 0;
  for (int i = lo; i < hi; ++i) {
    int v = cnt[i];
    row_ptr[i] = run;
    dinv[i] = 1.0f / sqrtf((float)(v + 1));     // +1 self-loop
    run += v;
  }
  if (tid == 255) row_ptr[n] = partial[255];
}

__global__ void fill_csr(const int* __restrict__ ei, int E,
                         const int* __restrict__ flag,
                         const int* __restrict__ row_ptr, int* __restrict__ cursor,
                         int* __restrict__ csr_src) {
  int e = blockIdx.x * blockDim.x + threadIdx.x;
  int is64 = *flag;
  if (e < E) {
    int s = is64 ? ei[2 * e] : ei[e];
    int d = is64 ? ei[2 * (E + e)] : ei[E + e];
    int pos = row_ptr[d] + atomicAdd(&cursor[d], 1);
    csr_src[pos] = s;
  }
}

// x f32 row-major -> A-fragment-major bf16 hi/lo. One thread per (row, k-octet):
// reads 32B coalesced, writes one 16B frag slot per plane.
__global__ void split_x_frag(const float4* __restrict__ in,
                             unsigned short* __restrict__ hi,
                             unsigned short* __restrict__ lo, int M) {
  int t = blockIdx.x * blockDim.x + threadIdx.x;
  if (t >= M * 32) return;
  int m = t >> 5, o = t & 31;              // o = k-octet
  float4 v0 = in[m * 64 + o * 2];
  float4 v1 = in[m * 64 + o * 2 + 1];
  float f[8] = {v0.x, v0.y, v0.z, v0.w, v1.x, v1.y, v1.z, v1.w};
  unsigned short hs[8], ls[8];
#pragma unroll
  for (int j = 0; j < 8; ++j) {
    unsigned short h = f32_to_bf16(f[j]);
    hs[j] = h;
    ls[j] = f32_to_bf16(f[j] - bf16_to_f32(h));
  }
  int addr = frag_addr(m, o * 8);
  *(ushort4*)(hi + addr) = make_ushort4(hs[0], hs[1], hs[2], hs[3]);
  *(ushort4*)(hi + addr + 4) = make_ushort4(hs[4], hs[5], hs[6], hs[7]);
  *(ushort4*)(lo + addr) = make_ushort4(ls[0], ls[1], ls[2], ls[3]);
  *(ushort4*)(lo + addr + 4) = make_ushort4(ls[4], ls[5], ls[6], ls[7]);
}

// W [k][n] row-major 256x256 -> B-fragment-major bf16 hi/lo.
__global__ void pack_w_frag(const float* __restrict__ W,
                            unsigned short* __restrict__ hi,
                            unsigned short* __restrict__ lo) {
  int k = blockIdx.x, n = threadIdx.x;
  float v = W[k * 256 + n];
  unsigned short h = f32_to_bf16(v);
  int addr = frag_addr(n, k);  // B-frag: same formula with n as row
  hi[addr] = h;
  lo[addr] = f32_to_bf16(v - bf16_to_f32(h));
}

// C = A @ B from fragment-major A [M,256] hi/lo and B [256,256] hi/lo.
// Block: 4 waves, tile 64m x 128n; wave (wm,wn) = 32m x 64n (2 x 4 frags).
// All loads: uniform base + lane*16B -> one coalesced 1KB burst each.
// MODE 0: f32 row-major out.  MODE 1: +bias, relu, A-fragment bf16 hi/lo out.
template <int MODE>
__global__ __launch_bounds__(256) void gemm_frag(
    const unsigned short* __restrict__ Ahi, const unsigned short* __restrict__ Alo,
    const unsigned short* __restrict__ Bhi, const unsigned short* __restrict__ Blo,
    int M, const float* __restrict__ bias, float* __restrict__ outf,
    unsigned short* __restrict__ outhi, unsigned short* __restrict__ outlo) {
  int wid = threadIdx.x >> 6, lane = threadIdx.x & 63;
  int wm = wid & 1, wn = wid >> 1;
  int Mtiles = (M + 15) >> 4;
  int mt_base = blockIdx.x * 4 + wm * 2;
  int nt_base = blockIdx.y * 8 + wn * 4;
  int la8 = lane * 8;

  int mt0 = mt_base < Mtiles ? mt_base : Mtiles - 1;
  int mt1 = mt_base + 1 < Mtiles ? mt_base + 1 : Mtiles - 1;
  const unsigned short* a0h = Ahi + mt0 * 4096 + la8;
  const unsigned short* a0l = Alo + mt0 * 4096 + la8;
  const unsigned short* a1h = Ahi + mt1 * 4096 + la8;
  const unsigned short* a1l = Alo + mt1 * 4096 + la8;
  const unsigned short* bh = Bhi + nt_base * 4096 + la8;
  const unsigned short* bl = Blo + nt_base * 4096 + la8;

  f32x4 acc[2][4] = {};
#pragma unroll
  for (int k0 = 0; k0 < 8; ++k0) {
    bf16x8 A0h = *(const bf16x8*)(a0h + k0 * 512);
    bf16x8 A0l = *(const bf16x8*)(a0l + k0 * 512);
    bf16x8 A1h = *(const bf16x8*)(a1h + k0 * 512);
    bf16x8 A1l = *(const bf16x8*)(a1l + k0 * 512);
#pragma unroll
    for (int ni = 0; ni < 4; ++ni) {
      bf16x8 Bh = *(const bf16x8*)(bh + ni * 4096 + k0 * 512);
      bf16x8 Bl = *(const bf16x8*)(bl + ni * 4096 + k0 * 512);
      acc[0][ni] = __builtin_amdgcn_mfma_f32_16x16x32_bf16(A0h, Bh, acc[0][ni], 0, 0, 0);
      acc[0][ni] = __builtin_amdgcn_mfma_f32_16x16x32_bf16(A0h, Bl, acc[0][ni], 0, 0, 0);
      acc[0][ni] = __builtin_amdgcn_mfma_f32_16x16x32_bf16(A0l, Bh, acc[0][ni], 0, 0, 0);
      acc[1][ni] = __builtin_amdgcn_mfma_f32_16x16x32_bf16(A1h, Bh, acc[1][ni], 0, 0, 0);
      acc[1][ni] = __builtin_amdgcn_mfma_f32_16x16x32_bf16(A1h, Bl, acc[1][ni], 0, 0, 0);
      acc[1][ni] = __builtin_amdgcn_mfma_f32_16x16x32_bf16(A1l, Bh, acc[1][ni], 0, 0, 0);
    }
  }

  int r = lane & 15, g = lane >> 4;
#pragma unroll
  for (int mi = 0; mi < 2; ++mi) {
#pragma unroll
    for (int ni = 0; ni < 4; ++ni) {
      int col = (nt_base + ni) * 16 + r;
      float bcol = (MODE == 1) ? bias[col] : 0.0f;
#pragma unroll
      for (int ii = 0; ii < 4; ++ii) {
        int row = (mt_base + mi) * 16 + g * 4 + ii;
        if (row < M) {
          float v = acc[mi][ni][ii];
          if (MODE == 1) {
            v = fmaxf(v + bcol, 0.0f);
            unsigned short h = f32_to_bf16(v);
            int addr = frag_addr(row, col);
            outhi[addr] = h;
            outlo[addr] = f32_to_bf16(v - bf16_to_f32(h));
          } else {
            outf[row * 256 + col] = v;
          }
        }
      }
    }
  }
}

// out[i] = b + dinv[i] * sum_{e in CSR(i)} dinv[src] * h[src] + dinv[i]^2 * h[i]
// One wave per node; lane handles cols [4*lane, 4*lane+4) as float4 (1KB/row).
// Edge loop x4-unrolled: 4 independent FMA chains / outstanding gathers.
// MODE 1: A-fragment bf16 hi/lo out (feeds next GEMM).
// MODE 2: fused classifier: logits[node] = (conv_out) @ Wcls + bcls.
template <int MODE>
__global__ __launch_bounds__(256) void gcn_conv(
    const float* __restrict__ h, const int* __restrict__ row_ptr,
    const int* __restrict__ csr_src, const float* __restrict__ dinv,
    const float* __restrict__ bias, int n_nodes, float* __restrict__ outf,
    unsigned short* __restrict__ outhi, unsigned short* __restrict__ outlo,
    const float* __restrict__ Wcls, const float* __restrict__ bcls) {
  int wid = threadIdx.x >> 6, lane = threadIdx.x & 63;
  int node = blockIdx.x * 4 + wid;
  if (node >= n_nodes) return;
  const float4* hp = (const float4*)h;
  float4 a0 = make_float4(0.f, 0.f, 0.f, 0.f);
  float4 a1 = make_float4(0.f, 0.f, 0.f, 0.f);
  float4 a2 = make_float4(0.f, 0.f, 0.f, 0.f);
  float4 a3 = make_float4(0.f, 0.f, 0.f, 0.f);
  int e0 = row_ptr[node], e1 = row_ptr[node + 1];
  int e = e0;
  for (; e + 3 < e1; e += 4) {
    int s0 = csr_src[e], s1 = csr_src[e + 1], s2 = csr_src[e + 2], s3 = csr_src[e + 3];
    float d0 = dinv[s0], d1 = dinv[s1], d2 = dinv[s2], d3 = dinv[s3];
    float4 v0 = hp[s0 * 64 + lane];
    float4 v1 = hp[s1 * 64 + lane];
    float4 v2 = hp[s2 * 64 + lane];
    float4 v3 = hp[s3 * 64 + lane];
    a0.x += d0 * v0.x; a0.y += d0 * v0.y; a0.z += d0 * v0.z; a0.w += d0 * v0.w;
    a1.x += d1 * v1.x; a1.y += d1 * v1.y; a1.z += d1 * v1.z; a1.w += d1 * v1.w;
    a2.x += d2 * v2.x; a2.y += d2 * v2.y; a2.z += d2 * v2.z; a2.w += d2 * v2.w;
    a3.x += d3 * v3.x; a3.y += d3 * v3.y; a3.z += d3 * v3.z; a3.w += d3 * v3.w;
  }
  for (; e < e1; ++e) {
    int s0 = csr_src[e];
    float d0 = dinv[s0];
    float4 v0 = hp[s0 * 64 + lane];
    a0.x += d0 * v0.x; a0.y += d0 * v0.y; a0.z += d0 * v0.z; a0.w += d0 * v0.w;
  }
  float di = dinv[node];
  float4 self = hp[node * 64 + lane];
  float4 b4 = ((const float4*)bias)[lane];
  float o[4];
  o[0] = di * (a0.x + a1.x + a2.x + a3.x) + di * di * self.x + b4.x;
  o[1] = di * (a0.y + a1.y + a2.y + a3.y) + di * di * self.y + b4.y;
  o[2] = di * (a0.z + a1.z + a2.z + a3.z) + di * di * self.z + b4.z;
  o[3] = di * (a0.w + a1.w + a2.w + a3.w) + di * di * self.w + b4.w;
  if (MODE == 1) {
    unsigned short hs[4], ls[4];
#pragma unroll
    for (int j = 0; j < 4; ++j) {
      unsigned short hh = f32_to_bf16(o[j]);
      hs[j] = hh;
      ls[j] = f32_to_bf16(o[j] - bf16_to_f32(hh));
    }
    // cols k = 4*lane..4*lane+3 of row `node`, fragment-major, 8B per plane
    int addr = frag_addr(node, lane * 4);
    *(ushort4*)(outhi + addr) = make_ushort4(hs[0], hs[1], hs[2], hs[3]);
    *(ushort4*)(outlo + addr) = make_ushort4(ls[0], ls[1], ls[2], ls[3]);
  } else if (MODE == 2) {
    // logits = o(row) @ Wcls[256,3] + bcls, wave shuffle-reduce (18 shfls)
    float s0 = 0.f, s1 = 0.f, s2 = 0.f;
#pragma unroll
    for (int j = 0; j < 4; ++j) {
      int k = lane * 4 + j;
      s0 += o[j] * Wcls[k * 3 + 0];
      s1 += o[j] * Wcls[k * 3 + 1];
      s2 += o[j] * Wcls[k * 3 + 2];
    }
#pragma unroll
    for (int sh = 32; sh > 0; sh >>= 1) {
      s0 += __shfl_down(s0, sh);
      s1 += __shfl_down(s1, sh);
      s2 += __shfl_down(s2, sh);
    }
    if (lane == 0) {
      outf[node * 3 + 0] = s0 + bcls[0];
      outf[node * 3 + 1] = s1 + bcls[1];
      outf[node * 3 + 2] = s2 + bcls[2];
    }
  } else {
    ((float4*)outf)[node * 64 + lane] = make_float4(o[0], o[1], o[2], o[3]);
  }
}

extern "C" void kernel_launch(void* const* d_in, const int* in_sizes, int n_in,
                              void* d_out, int out_size, void* d_ws, size_t ws_size,
                              hipStream_t stream) {
  const float* x = (const float*)d_in[0];
  const int* ei = (const int*)d_in[1];
  const float* W_embed = (const float*)d_in[2];
  const float* b_embed = (const float*)d_in[3];
  const float* W1 = (const float*)d_in[4];
  const float* b1 = (const float*)d_in[5];
  const float* W2 = (const float*)d_in[6];
  const float* b2 = (const float*)d_in[7];
  const float* Wcls = (const float*)d_in[8];
  const float* bcls = (const float*)d_in[9];
  const int N = in_sizes[0] / 256;   // 20000
  const int E = in_sizes[1] / 2;     // 320000

  char* ws = (char*)d_ws;
  size_t off = 0;
  auto alloc = [&](size_t bytes) {
    void* p = ws + off;
    off = (off + bytes + 255) & ~(size_t)255;
    return p;
  };
  int* cnt = (int*)alloc((size_t)N * 4);
  int* cursor = (int*)alloc((size_t)N * 4);
  int* row_ptr = (int*)alloc((size_t)(N + 1) * 4);
  float* dinv = (float*)alloc((size_t)N * 4);
  int* csr_src = (int*)alloc((size_t)E * 4);
  int* flag = (int*)alloc(256);
  unsigned short* WemFhi = (unsigned short*)alloc(256 * 256 * 2);
  unsigned short* WemFlo = (unsigned short*)alloc(256 * 256 * 2);
  unsigned short* W1Fhi = (unsigned short*)alloc(256 * 256 * 2);
  unsigned short* W1Flo = (unsigned short*)alloc(256 * 256 * 2);
  unsigned short* W2Fhi = (unsigned short*)alloc(256 * 256 * 2);
  unsigned short* W2Flo = (unsigned short*)alloc(256 * 256 * 2);
  size_t big = (size_t)N * 256;
  // P1: x frags, reused as h2 frags. P2: h0 frags, reused h3 f32. P3: h1 f32.
  unsigned short* P1hi = (unsigned short*)alloc(big * 4);
  unsigned short* P1lo = P1hi + big;
  unsigned short* P2hi = (unsigned short*)alloc(big * 4);
  unsigned short* P2lo = P2hi + big;
  float* P2f = (float*)P2hi;
  float* P3f = (float*)alloc(big * 4);

  int nz = (int)(((char*)row_ptr - (char*)cnt) / 4);  // cnt + cursor (incl pad)
  zero_ints<<<(nz + 255) / 256, 256, 0, stream>>>(cnt, nz);
  detect_i64<<<1, 256, 0, stream>>>((const unsigned int*)ei, 4096, flag);
  count_deg<<<(E + 255) / 256, 256, 0, stream>>>(ei, E, flag, cnt);
  scan_rowptr<<<1, 256, 0, stream>>>(cnt, row_ptr, dinv, N);
  fill_csr<<<(E + 255) / 256, 256, 0, stream>>>(ei, E, flag, row_ptr, cursor, csr_src);

  split_x_frag<<<(N * 32 + 255) / 256, 256, 0, stream>>>((const float4*)x, P1hi, P1lo, N);
  pack_w_frag<<<256, 256, 0, stream>>>(W_embed, WemFhi, WemFlo);
  pack_w_frag<<<256, 256, 0, stream>>>(W1, W1Fhi, W1Flo);
  pack_w_frag<<<256, 256, 0, stream>>>(W2, W2Fhi, W2Flo);

  dim3 gg((N + 63) / 64, 2);  // 64 rows x 128 cols per block
  // h0 = relu(x@We + be)  -> P2 frags
  gemm_frag<1><<<gg, 256, 0, stream>>>(P1hi, P1lo, WemFhi, WemFlo, N, b_embed,
                                       nullptr, P2hi, P2lo);
  // h1 = h0@W1 -> P3 f32
  gemm_frag<0><<<gg, 256, 0, stream>>>(P2hi, P2lo, W1Fhi, W1Flo, N, nullptr,
                                       P3f, nullptr, nullptr);
  // h2 = conv(h1) + b1 -> P1 frags
  gcn_conv<1><<<(N + 3) / 4, 256, 0, stream>>>(P3f, row_ptr, csr_src, dinv, b1, N,
                                               nullptr, P1hi, P1lo, nullptr, nullptr);
  // h3 = h2@W2 -> P2 f32
  gemm_frag<0><<<gg, 256, 0, stream>>>(P1hi, P1lo, W2Fhi, W2Flo, N, nullptr,
                                       P2f, nullptr, nullptr);
  // logits = (conv(h3) + b2) @ Wcls + bcls -> d_out  (fused classifier)
  gcn_conv<2><<<(N + 3) / 4, 256, 0, stream>>>(P2f, row_ptr, csr_src, dinv, b2, N,
                                               (float*)d_out, nullptr, nullptr,
                                               Wcls, bcls);
}

// Round 12
// 284.091 us; speedup vs baseline: 1.5278x; 1.1570x over previous
//
#include <hip/hip_runtime.h>
#include <stdint.h>

// GCN forward on MI355X.
// R6 algebraic restructure: GCNConv is linear, so
//   logits = S(h1 W2) Wc + (b2 Wc + bc) = S(h1 (W2 Wc)) + bvec
// => conv2 aggregates only 3 cols (gather 348MB -> 4MB), GEMM3 deleted,
//    h1 never materialized (conv1 epilogue folds the 256x3 W2Wc dot).
// R10: conv1 gather unroll x8 (8 indep chains) — diagnoses latency- vs
//    traffic-bound: dur+BW move => latency; flat => L2-miss ceiling.
// Pipeline: CSR build -> pack x,We,W1 frags -> W2Wc/bvec -> GEMM1 (relu,
//   frag out) -> GEMM2 (f32 out, rows pre-scaled by dinv) -> conv1 fused
//   (aggregate + b1 + dot W2Wc -> t' [N,4]) -> conv2_skinny (-> logits).
//
// R2 lesson: scattered fragment loads = VMEM-issue bound. Fix: frag-major
// storage, every GEMM load is uniform base + 16*lane (1KB burst).
// R6 lesson: conv = gather-traffic bound (FETCH 147MB vs 20MB unique).

typedef __attribute__((ext_vector_type(8))) __bf16 bf16x8;
typedef __attribute__((ext_vector_type(4))) float f32x4;

static __device__ __forceinline__ unsigned short f32_to_bf16(float f) {
  uint32_t u = __float_as_uint(f);
  u += 0x7fffu + ((u >> 16) & 1u);   // RNE (finite data)
  return (unsigned short)(u >> 16);
}
static __device__ __forceinline__ float bf16_to_f32(unsigned short h) {
  return __uint_as_float(((uint32_t)h) << 16);
}
static __device__ __forceinline__ int frag_addr(int m, int k) {
  return (((m >> 4) * 8 + (k >> 5)) << 9) + (((m & 15) + 16 * ((k >> 3) & 3)) << 3) + (k & 7);
}

__global__ void zero_ints(int* __restrict__ p, int n) {
  int i = blockIdx.x * blockDim.x + threadIdx.x;
  if (i < n) p[i] = 0;
}

// edge_index may arrive as int32 or int64; detect on-device (values < 2^31,
// so an int64 array has every odd dword == 0 little-endian).
__global__ void detect_i64(const unsigned int* __restrict__ ei, int nwords,
                           int* __restrict__ flag) {
  __shared__ int any;
  if (threadIdx.x == 0) any = 0;
  __syncthreads();
  for (int i = 1 + 2 * (int)threadIdx.x; i < nwords; i += 2 * blockDim.x)
    if (ei[i] != 0u) any = 1;
  __syncthreads();
  if (threadIdx.x == 0) *flag = (any == 0) ? 1 : 0;
}

__global__ void count_deg(const int* __restrict__ ei, int E,
                          const int* __restrict__ flag, int* __restrict__ cnt) {
  int e = blockIdx.x * blockDim.x + threadIdx.x;
  int is64 = *flag;
  if (e < E) {
    int d = is64 ? ei[2 * (E + e)] : ei[E + e];
    atomicAdd(&cnt[d], 1);
  }
}

// Exclusive scan of cnt -> row_ptr, plus dinv = 1/sqrt(deg+1).
__global__ __launch_bounds__(256) void scan_rowptr(
    const int* __restrict__ cnt, int* __restrict__ row_ptr,
    float* __restrict__ dinv, int n) {
  __shared__ int partial[256];
  int tid = threadIdx.x;
  int per = (n + 255) / 256;
  int lo = tid * per;
  int hi = lo + per; if (hi > n) hi = n;
  int s = 0;
  for (int i = lo; i < hi; ++i) s += cnt[i];
  partial[tid] = s;
  __syncthreads();
  for (int off = 1; off < 256; off <<= 1) {
    int t = (tid >= off) ? partial[tid - off] : 0;
    __syncthreads();
    partial[tid] += t;
    __syncthreads();
  }
  int run = (tid > 0) ? partial[tid - 1] : 0;
  for (int i = lo; i < hi; ++i) {
    int v = cnt[i];
    row_ptr[i] = run;
    dinv[i] = 1.0f / sqrtf((float)(v + 1));     // +1 self-loop
    run += v;
  }
  if (tid == 255) row_ptr[n] = partial[255];
}

__global__ void fill_csr(const int* __restrict__ ei, int E,
                         const int* __restrict__ flag,
                         const int* __restrict__ row_ptr, int* __restrict__ cursor,
                         int* __restrict__ csr_src) {
  int e = blockIdx.x * blockDim.x + threadIdx.x;
  int is64 = *flag;
  if (e < E) {
    int s = is64 ? ei[2 * e] : ei[e];
    int d = is64 ? ei[2 * (E + e)] : ei[E + e];
    int pos = row_ptr[d] + atomicAdd(&cursor[d], 1);
    csr_src[pos] = s;
  }
}

// x f32 row-major -> A-fragment-major bf16 hi/lo.
__global__ void split_x_frag(const float4* __restrict__ in,
                             unsigned short* __restrict__ hi,
                             unsigned short* __restrict__ lo, int M) {
  int t = blockIdx.x * blockDim.x + threadIdx.x;
  if (t >= M * 32) return;
  int m = t >> 5, o = t & 31;              // o = k-octet
  float4 v0 = in[m * 64 + o * 2];
  float4 v1 = in[m * 64 + o * 2 + 1];
  float f[8] = {v0.x, v0.y, v0.z, v0.w, v1.x, v1.y, v1.z, v1.w};
  unsigned short hs[8], ls[8];
#pragma unroll
  for (int j = 0; j < 8; ++j) {
    unsigned short h = f32_to_bf16(f[j]);
    hs[j] = h;
    ls[j] = f32_to_bf16(f[j] - bf16_to_f32(h));
  }
  int addr = frag_addr(m, o * 8);
  *(ushort4*)(hi + addr) = make_ushort4(hs[0], hs[1], hs[2], hs[3]);
  *(ushort4*)(hi + addr + 4) = make_ushort4(hs[4], hs[5], hs[6], hs[7]);
  *(ushort4*)(lo + addr) = make_ushort4(ls[0], ls[1], ls[2], ls[3]);
  *(ushort4*)(lo + addr + 4) = make_ushort4(ls[4], ls[5], ls[6], ls[7]);
}

// W [k][n] row-major 256x256 -> B-fragment-major bf16 hi/lo.
__global__ void pack_w_frag(const float* __restrict__ W,
                            unsigned short* __restrict__ hi,
                            unsigned short* __restrict__ lo) {
  int k = blockIdx.x, n = threadIdx.x;
  float v = W[k * 256 + n];
  unsigned short h = f32_to_bf16(v);
  int addr = frag_addr(n, k);  // B-frag: same formula with n as row
  hi[addr] = h;
  lo[addr] = f32_to_bf16(v - bf16_to_f32(h));
}

// w2wc[k][c] = (W2 @ Wc)[k][c]  (256x3, f32);  bvec = b2 @ Wc + bc  (3).
__global__ void build_w2wc(const float* __restrict__ W2, const float* __restrict__ Wc,
                           const float* __restrict__ b2, const float* __restrict__ bc,
                           float* __restrict__ w2wc, float* __restrict__ bvec) {
  int k = threadIdx.x;  // 256 threads
  float s0 = 0.f, s1 = 0.f, s2 = 0.f;
  for (int n = 0; n < 256; ++n) {
    float w = W2[k * 256 + n];
    s0 += w * Wc[n * 3 + 0];
    s1 += w * Wc[n * 3 + 1];
    s2 += w * Wc[n * 3 + 2];
  }
  w2wc[k * 3 + 0] = s0;
  w2wc[k * 3 + 1] = s1;
  w2wc[k * 3 + 2] = s2;
  if (k < 3) {
    float s = bc[k];
    for (int n = 0; n < 256; ++n) s += b2[n] * Wc[n * 3 + k];
    bvec[k] = s;
  }
}

// C = A @ B from fragment-major A [M,256] hi/lo and B [256,256] hi/lo.
// Block: 4 waves, tile 64m x 128n; wave (wm,wn) = 32m x 64n (2 x 4 frags).
// All loads: uniform base + lane*16B -> one coalesced 1KB burst each.
// MODE 1: +bias, relu, A-fragment bf16 hi/lo out.
// MODE 3: f32 row-major out, each row scaled by rowscale[row] (dinv pre-scale).
template <int MODE>
__global__ __launch_bounds__(256) void gemm_frag(
    const unsigned short* __restrict__ Ahi, const unsigned short* __restrict__ Alo,
    const unsigned short* __restrict__ Bhi, const unsigned short* __restrict__ Blo,
    int M, const float* __restrict__ bias, float* __restrict__ outf,
    unsigned short* __restrict__ outhi, unsigned short* __restrict__ outlo,
    const float* __restrict__ rowscale) {
  int wid = threadIdx.x >> 6, lane = threadIdx.x & 63;
  int wm = wid & 1, wn = wid >> 1;
  int Mtiles = (M + 15) >> 4;
  int mt_base = blockIdx.x * 4 + wm * 2;
  int nt_base = blockIdx.y * 8 + wn * 4;
  int la8 = lane * 8;

  int mt0 = mt_base < Mtiles ? mt_base : Mtiles - 1;
  int mt1 = mt_base + 1 < Mtiles ? mt_base + 1 : Mtiles - 1;
  const unsigned short* a0h = Ahi + mt0 * 4096 + la8;
  const unsigned short* a0l = Alo + mt0 * 4096 + la8;
  const unsigned short* a1h = Ahi + mt1 * 4096 + la8;
  const unsigned short* a1l = Alo + mt1 * 4096 + la8;
  const unsigned short* bh = Bhi + nt_base * 4096 + la8;
  const unsigned short* bl = Blo + nt_base * 4096 + la8;

  f32x4 acc[2][4] = {};
#pragma unroll
  for (int k0 = 0; k0 < 8; ++k0) {
    bf16x8 A0h = *(const bf16x8*)(a0h + k0 * 512);
    bf16x8 A0l = *(const bf16x8*)(a0l + k0 * 512);
    bf16x8 A1h = *(const bf16x8*)(a1h + k0 * 512);
    bf16x8 A1l = *(const bf16x8*)(a1l + k0 * 512);
#pragma unroll
    for (int ni = 0; ni < 4; ++ni) {
      bf16x8 Bh = *(const bf16x8*)(bh + ni * 4096 + k0 * 512);
      bf16x8 Bl = *(const bf16x8*)(bl + ni * 4096 + k0 * 512);
      acc[0][ni] = __builtin_amdgcn_mfma_f32_16x16x32_bf16(A0h, Bh, acc[0][ni], 0, 0, 0);
      acc[0][ni] = __builtin_amdgcn_mfma_f32_16x16x32_bf16(A0h, Bl, acc[0][ni], 0, 0, 0);
      acc[0][ni] = __builtin_amdgcn_mfma_f32_16x16x32_bf16(A0l, Bh, acc[0][ni], 0, 0, 0);
      acc[1][ni] = __builtin_amdgcn_mfma_f32_16x16x32_bf16(A1h, Bh, acc[1][ni], 0, 0, 0);
      acc[1][ni] = __builtin_amdgcn_mfma_f32_16x16x32_bf16(A1h, Bl, acc[1][ni], 0, 0, 0);
      acc[1][ni] = __builtin_amdgcn_mfma_f32_16x16x32_bf16(A1l, Bh, acc[1][ni], 0, 0, 0);
    }
  }

  int r = lane & 15, g = lane >> 4;
#pragma unroll
  for (int mi = 0; mi < 2; ++mi) {
#pragma unroll
    for (int ii = 0; ii < 4; ++ii) {
      int row = (mt_base + mi) * 16 + g * 4 + ii;
      if (row >= M) continue;
      float rs = (MODE == 3) ? rowscale[row] : 1.0f;
#pragma unroll
      for (int ni = 0; ni < 4; ++ni) {
        int col = (nt_base + ni) * 16 + r;
        float v = acc[mi][ni][ii];
        if (MODE == 1) {
          v = fmaxf(v + bias[col], 0.0f);
          unsigned short h = f32_to_bf16(v);
          int addr = frag_addr(row, col);
          outhi[addr] = h;
          outlo[addr] = f32_to_bf16(v - bf16_to_f32(h));
        } else {
          outf[row * 256 + col] = v * rs;
        }
      }
    }
  }
}

// conv1 fused: t'[i] = dinv[i] * ( h1[i] @ w2wc ),
//   h1[i] = dinv[i]*(sum_{e in CSR(i)} g'[src] + g'[i]) + b1,  g' = dinv-scaled g1.
// One wave per node; lane owns cols [4*lane,4*lane+4).
// R10: x8-unrolled gather — 8 independent chains / outstanding 128B gathers
// (statically indexed; rule-#20-safe via #pragma unroll).
__global__ __launch_bounds__(256) void gcn_conv_fused(
    const float* __restrict__ g, const int* __restrict__ row_ptr,
    const int* __restrict__ csr_src, const float* __restrict__ dinv,
    const float* __restrict__ b1, const float* __restrict__ w2wc,
    int n_nodes, float4* __restrict__ t4) {
  int wid = threadIdx.x >> 6, lane = threadIdx.x & 63;
  int node = blockIdx.x * 4 + wid;
  if (node >= n_nodes) return;
  const float4* hp = (const float4*)g;
  float4 a[8];
#pragma unroll
  for (int u = 0; u < 8; ++u) a[u] = make_float4(0.f, 0.f, 0.f, 0.f);
  int e0 = row_ptr[node], e1 = row_ptr[node + 1];
  int e = e0;
  for (; e + 7 < e1; e += 8) {
    int s[8];
#pragma unroll
    for (int u = 0; u < 8; ++u) s[u] = csr_src[e + u];
#pragma unroll
    for (int u = 0; u < 8; ++u) {
      float4 v = hp[s[u] * 64 + lane];
      a[u].x += v.x; a[u].y += v.y; a[u].z += v.z; a[u].w += v.w;
    }
  }
  for (; e + 3 < e1; e += 4) {
    int s[4];
#pragma unroll
    for (int u = 0; u < 4; ++u) s[u] = csr_src[e + u];
#pragma unroll
    for (int u = 0; u < 4; ++u) {
      float4 v = hp[s[u] * 64 + lane];
      a[u].x += v.x; a[u].y += v.y; a[u].z += v.z; a[u].w += v.w;
    }
  }
  for (; e < e1; ++e) {
    float4 v = hp[csr_src[e] * 64 + lane];
    a[0].x += v.x; a[0].y += v.y; a[0].z += v.z; a[0].w += v.w;
  }
  // tree-sum the 8 accumulators
#pragma unroll
  for (int u = 0; u < 4; ++u) {
    a[u].x += a[u + 4].x; a[u].y += a[u + 4].y;
    a[u].z += a[u + 4].z; a[u].w += a[u + 4].w;
  }
  a[0].x += a[2].x; a[0].y += a[2].y; a[0].z += a[2].z; a[0].w += a[2].w;
  a[1].x += a[3].x; a[1].y += a[3].y; a[1].z += a[3].z; a[1].w += a[3].w;
  a[0].x += a[1].x; a[0].y += a[1].y; a[0].z += a[1].z; a[0].w += a[1].w;

  float4 self = hp[node * 64 + lane];      // g'[node] = dinv[node]*g1[node]
  float di = dinv[node];
  float4 b4 = ((const float4*)b1)[lane];
  float o[4];
  o[0] = di * (a[0].x + self.x) + b4.x;
  o[1] = di * (a[0].y + self.y) + b4.y;
  o[2] = di * (a[0].z + self.z) + b4.z;
  o[3] = di * (a[0].w + self.w) + b4.w;
  // t = h1 @ w2wc (256x3), then pre-scale by di for conv2.
  float s0 = 0.f, s1 = 0.f, s2 = 0.f;
#pragma unroll
  for (int j = 0; j < 4; ++j) {
    int k = lane * 4 + j;
    s0 += o[j] * w2wc[k * 3 + 0];
    s1 += o[j] * w2wc[k * 3 + 1];
    s2 += o[j] * w2wc[k * 3 + 2];
  }
#pragma unroll
  for (int sh = 32; sh > 0; sh >>= 1) {
    s0 += __shfl_down(s0, sh);
    s1 += __shfl_down(s1, sh);
    s2 += __shfl_down(s2, sh);
  }
  if (lane == 0) t4[node] = make_float4(di * s0, di * s1, di * s2, 0.f);
}

// conv2 on 3 columns: logits[i] = dinv[i]*(sum t'[src] + t'[i]) + bvec.
// One thread per node; x2-unrolled 16B gathers (4MB total).
__global__ void conv2_skinny(const float4* __restrict__ t4,
                             const int* __restrict__ row_ptr,
                             const int* __restrict__ csr_src,
                             const float* __restrict__ dinv,
                             const float* __restrict__ bvec,
                             float* __restrict__ out, int n) {
  int i = blockIdx.x * blockDim.x + threadIdx.x;
  if (i >= n) return;
  int e = row_ptr[i], e1 = row_ptr[i + 1];
  float a0 = 0.f, a1 = 0.f, a2 = 0.f;
  float b0 = 0.f, b1 = 0.f, b2 = 0.f;
  for (; e + 1 < e1; e += 2) {
    float4 v0 = t4[csr_src[e]];
    float4 v1 = t4[csr_src[e + 1]];
    a0 += v0.x; a1 += v0.y; a2 += v0.z;
    b0 += v1.x; b1 += v1.y; b2 += v1.z;
  }
  if (e < e1) {
    float4 v0 = t4[csr_src[e]];
    a0 += v0.x; a1 += v0.y; a2 += v0.z;
  }
  float4 self = t4[i];
  float di = dinv[i];
  out[i * 3 + 0] = di * (a0 + b0 + self.x) + bvec[0];
  out[i * 3 + 1] = di * (a1 + b1 + self.y) + bvec[1];
  out[i * 3 + 2] = di * (a2 + b2 + self.z) + bvec[2];
}

extern "C" void kernel_launch(void* const* d_in, const int* in_sizes, int n_in,
                              void* d_out, int out_size, void* d_ws, size_t ws_size,
                              hipStream_t stream) {
  const float* x = (const float*)d_in[0];
  const int* ei = (const int*)d_in[1];
  const float* W_embed = (const float*)d_in[2];
  const float* b_embed = (const float*)d_in[3];
  const float* W1 = (const float*)d_in[4];
  const float* b1 = (const float*)d_in[5];
  const float* W2 = (const float*)d_in[6];
  const float* b2 = (const float*)d_in[7];
  const float* Wcls = (const float*)d_in[8];
  const float* bcls = (const float*)d_in[9];
  const int N = in_sizes[0] / 256;   // 20000
  const int E = in_sizes[1] / 2;     // 320000

  char* ws = (char*)d_ws;
  size_t off = 0;
  auto alloc = [&](size_t bytes) {
    void* p = ws + off;
    off = (off + bytes + 255) & ~(size_t)255;
    return p;
  };
  int* cnt = (int*)alloc((size_t)N * 4);
  int* cursor = (int*)alloc((size_t)N * 4);
  int* row_ptr = (int*)alloc((size_t)(N + 1) * 4);
  float* dinv = (float*)alloc((size_t)N * 4);
  int* csr_src = (int*)alloc((size_t)E * 4);
  int* flag = (int*)alloc(256);
  unsigned short* WemFhi = (unsigned short*)alloc(256 * 256 * 2);
  unsigned short* WemFlo = (unsigned short*)alloc(256 * 256 * 2);
  unsigned short* W1Fhi = (unsigned short*)alloc(256 * 256 * 2);
  unsigned short* W1Flo = (unsigned short*)alloc(256 * 256 * 2);
  float* w2wc = (float*)alloc(256 * 3 * 4);
  float* bvec = (float*)alloc(256);
  float4* t4 = (float4*)alloc((size_t)N * 16);
  size_t big = (size_t)N * 256;
  unsigned short* P1hi = (unsigned short*)alloc(big * 4);  // x frags (hi|lo)
  unsigned short* P1lo = P1hi + big;
  unsigned short* P2hi = (unsigned short*)alloc(big * 4);  // h0 frags (hi|lo)
  unsigned short* P2lo = P2hi + big;
  float* P3f = (float*)alloc(big * 4);                     // g1' f32

  int nz = (int)(((char*)row_ptr - (char*)cnt) / 4);  // cnt + cursor (incl pad)
  zero_ints<<<(nz + 255) / 256, 256, 0, stream>>>(cnt, nz);
  detect_i64<<<1, 256, 0, stream>>>((const unsigned int*)ei, 4096, flag);
  count_deg<<<(E + 255) / 256, 256, 0, stream>>>(ei, E, flag, cnt);
  scan_rowptr<<<1, 256, 0, stream>>>(cnt, row_ptr, dinv, N);
  fill_csr<<<(E + 255) / 256, 256, 0, stream>>>(ei, E, flag, row_ptr, cursor, csr_src);

  split_x_frag<<<(N * 32 + 255) / 256, 256, 0, stream>>>((const float4*)x, P1hi, P1lo, N);
  pack_w_frag<<<256, 256, 0, stream>>>(W_embed, WemFhi, WemFlo);
  pack_w_frag<<<256, 256, 0, stream>>>(W1, W1Fhi, W1Flo);
  build_w2wc<<<1, 256, 0, stream>>>(W2, Wcls, b2, bcls, w2wc, bvec);

  dim3 gg((N + 63) / 64, 2);  // 64 rows x 128 cols per block
  // h0 = relu(x@We + be)  -> P2 frags
  gemm_frag<1><<<gg, 256, 0, stream>>>(P1hi, P1lo, WemFhi, WemFlo, N, b_embed,
                                       nullptr, P2hi, P2lo, nullptr);
  // g1' = dinv-rowscaled (h0@W1) -> P3f f32
  gemm_frag<3><<<gg, 256, 0, stream>>>(P2hi, P2lo, W1Fhi, W1Flo, N, nullptr,
                                       P3f, nullptr, nullptr, dinv);
  // t' = dinv * ((S g1 + b1) @ W2Wc)  -> t4 [N,4]
  gcn_conv_fused<<<(N + 3) / 4, 256, 0, stream>>>(P3f, row_ptr, csr_src, dinv, b1,
                                                  w2wc, N, t4);
  // logits = dinv*(sum t' + t'self) + bvec -> d_out
  conv2_skinny<<<(N + 255) / 256, 256, 0, stream>>>(t4, row_ptr, csr_src, dinv,
                                                    bvec, (float*)d_out, N);
}

// Round 13
// 245.044 us; speedup vs baseline: 1.7713x; 1.1593x over previous
//
#include <hip/hip_runtime.h>
#include <stdint.h>

// GCN forward on MI355X.
// R6: algebraic restructure (GCNConv linear => logits = S(h1 (W2 Wc)) + bvec):
//   conv2 aggregates only 3 cols, GEMM3 deleted, h1 never materialized.
// R10: conv1 gather unroll x8. R12 result: conv1/conv2/GEMMs all <46us,
//   but single-block scan_rowptr = 46.5us top dispatch (1-CU latency trap:
//   158 serial L2 loads x ~700cy, 0.05% HBM, 0.04% VALU).
// R12 fix: 3-kernel parallel scan (block-sums -> scan partials -> finalize).
//
// R2 lesson: scattered fragment loads = VMEM-issue bound -> frag-major storage.
// R6 lesson: conv = gather-traffic bound (FETCH 147MB vs 20MB unique).

typedef __attribute__((ext_vector_type(8))) __bf16 bf16x8;
typedef __attribute__((ext_vector_type(4))) float f32x4;

static __device__ __forceinline__ unsigned short f32_to_bf16(float f) {
  uint32_t u = __float_as_uint(f);
  u += 0x7fffu + ((u >> 16) & 1u);   // RNE (finite data)
  return (unsigned short)(u >> 16);
}
static __device__ __forceinline__ float bf16_to_f32(unsigned short h) {
  return __uint_as_float(((uint32_t)h) << 16);
}
static __device__ __forceinline__ int frag_addr(int m, int k) {
  return (((m >> 4) * 8 + (k >> 5)) << 9) + (((m & 15) + 16 * ((k >> 3) & 3)) << 3) + (k & 7);
}

__global__ void zero_ints(int* __restrict__ p, int n) {
  int i = blockIdx.x * blockDim.x + threadIdx.x;
  if (i < n) p[i] = 0;
}

// edge_index may arrive as int32 or int64; detect on-device (values < 2^31,
// so an int64 array has every odd dword == 0 little-endian).
__global__ void detect_i64(const unsigned int* __restrict__ ei, int nwords,
                           int* __restrict__ flag) {
  __shared__ int any;
  if (threadIdx.x == 0) any = 0;
  __syncthreads();
  for (int i = 1 + 2 * (int)threadIdx.x; i < nwords; i += 2 * blockDim.x)
    if (ei[i] != 0u) any = 1;
  __syncthreads();
  if (threadIdx.x == 0) *flag = (any == 0) ? 1 : 0;
}

__global__ void count_deg(const int* __restrict__ ei, int E,
                          const int* __restrict__ flag, int* __restrict__ cnt) {
  int e = blockIdx.x * blockDim.x + threadIdx.x;
  int is64 = *flag;
  if (e < E) {
    int d = is64 ? ei[2 * (E + e)] : ei[E + e];
    atomicAdd(&cnt[d], 1);
  }
}

// --- R12 parallel scan (replaces 46.5us single-block scan_rowptr) ---
// A: per-256-chunk sums.
__global__ __launch_bounds__(256) void scan_partials(
    const int* __restrict__ cnt, int* __restrict__ partials, int n) {
  __shared__ int sdata[256];
  int i = blockIdx.x * 256 + threadIdx.x;
  sdata[threadIdx.x] = (i < n) ? cnt[i] : 0;
  __syncthreads();
  for (int off = 128; off > 0; off >>= 1) {
    if (threadIdx.x < off) sdata[threadIdx.x] += sdata[threadIdx.x + off];
    __syncthreads();
  }
  if (threadIdx.x == 0) partials[blockIdx.x] = sdata[0];
}

// B: in-place inclusive scan of nb partials (nb <= 1024), one block.
__global__ __launch_bounds__(1024) void scan_offsets(int* __restrict__ partials,
                                                     int nb) {
  __shared__ int sdata[1024];
  int tid = threadIdx.x;
  sdata[tid] = (tid < nb) ? partials[tid] : 0;
  __syncthreads();
  for (int off = 1; off < 1024; off <<= 1) {
    int t = (tid >= off) ? sdata[tid - off] : 0;
    __syncthreads();
    sdata[tid] += t;
    __syncthreads();
  }
  if (tid < nb) partials[tid] = sdata[tid];
}

// C: block-local exclusive scan + chunk offset -> row_ptr, dinv.
__global__ __launch_bounds__(256) void scan_finalize(
    const int* __restrict__ cnt, const int* __restrict__ partials_inc,
    int* __restrict__ row_ptr, float* __restrict__ dinv, int n) {
  __shared__ int sdata[256];
  int b = blockIdx.x;
  int i = b * 256 + threadIdx.x;
  int v = (i < n) ? cnt[i] : 0;
  sdata[threadIdx.x] = v;
  __syncthreads();
  for (int off = 1; off < 256; off <<= 1) {
    int t = (threadIdx.x >= off) ? sdata[threadIdx.x - off] : 0;
    __syncthreads();
    sdata[threadIdx.x] += t;
    __syncthreads();
  }
  int incl = sdata[threadIdx.x];
  int base = (b > 0) ? partials_inc[b - 1] : 0;
  if (i < n) {
    row_ptr[i] = base + incl - v;                // exclusive prefix
    dinv[i] = 1.0f / sqrtf((float)(v + 1));      // +1 self-loop
    if (i == n - 1) row_ptr[n] = base + incl;    // total
  }
}

__global__ void fill_csr(const int* __restrict__ ei, int E,
                         const int* __restrict__ flag,
                         const int* __restrict__ row_ptr, int* __restrict__ cursor,
                         int* __restrict__ csr_src) {
  int e = blockIdx.x * blockDim.x + threadIdx.x;
  int is64 = *flag;
  if (e < E) {
    int s = is64 ? ei[2 * e] : ei[e];
    int d = is64 ? ei[2 * (E + e)] : ei[E + e];
    int pos = row_ptr[d] + atomicAdd(&cursor[d], 1);
    csr_src[pos] = s;
  }
}

// x f32 row-major -> A-fragment-major bf16 hi/lo.
__global__ void split_x_frag(const float4* __restrict__ in,
                             unsigned short* __restrict__ hi,
                             unsigned short* __restrict__ lo, int M) {
  int t = blockIdx.x * blockDim.x + threadIdx.x;
  if (t >= M * 32) return;
  int m = t >> 5, o = t & 31;              // o = k-octet
  float4 v0 = in[m * 64 + o * 2];
  float4 v1 = in[m * 64 + o * 2 + 1];
  float f[8] = {v0.x, v0.y, v0.z, v0.w, v1.x, v1.y, v1.z, v1.w};
  unsigned short hs[8], ls[8];
#pragma unroll
  for (int j = 0; j < 8; ++j) {
    unsigned short h = f32_to_bf16(f[j]);
    hs[j] = h;
    ls[j] = f32_to_bf16(f[j] - bf16_to_f32(h));
  }
  int addr = frag_addr(m, o * 8);
  *(ushort4*)(hi + addr) = make_ushort4(hs[0], hs[1], hs[2], hs[3]);
  *(ushort4*)(hi + addr + 4) = make_ushort4(hs[4], hs[5], hs[6], hs[7]);
  *(ushort4*)(lo + addr) = make_ushort4(ls[0], ls[1], ls[2], ls[3]);
  *(ushort4*)(lo + addr + 4) = make_ushort4(ls[4], ls[5], ls[6], ls[7]);
}

// W [k][n] row-major 256x256 -> B-fragment-major bf16 hi/lo.
__global__ void pack_w_frag(const float* __restrict__ W,
                            unsigned short* __restrict__ hi,
                            unsigned short* __restrict__ lo) {
  int k = blockIdx.x, n = threadIdx.x;
  float v = W[k * 256 + n];
  unsigned short h = f32_to_bf16(v);
  int addr = frag_addr(n, k);  // B-frag: same formula with n as row
  hi[addr] = h;
  lo[addr] = f32_to_bf16(v - bf16_to_f32(h));
}

// w2wc[k][c] = (W2 @ Wc)[k][c]  (256x3, f32);  bvec = b2 @ Wc + bc  (3).
__global__ void build_w2wc(const float* __restrict__ W2, const float* __restrict__ Wc,
                           const float* __restrict__ b2, const float* __restrict__ bc,
                           float* __restrict__ w2wc, float* __restrict__ bvec) {
  int k = threadIdx.x;  // 256 threads
  float s0 = 0.f, s1 = 0.f, s2 = 0.f;
  for (int n = 0; n < 256; ++n) {
    float w = W2[k * 256 + n];
    s0 += w * Wc[n * 3 + 0];
    s1 += w * Wc[n * 3 + 1];
    s2 += w * Wc[n * 3 + 2];
  }
  w2wc[k * 3 + 0] = s0;
  w2wc[k * 3 + 1] = s1;
  w2wc[k * 3 + 2] = s2;
  if (k < 3) {
    float s = bc[k];
    for (int n = 0; n < 256; ++n) s += b2[n] * Wc[n * 3 + k];
    bvec[k] = s;
  }
}

// C = A @ B from fragment-major A [M,256] hi/lo and B [256,256] hi/lo.
// Block: 4 waves, tile 64m x 128n; wave (wm,wn) = 32m x 64n (2 x 4 frags).
// All loads: uniform base + lane*16B -> one coalesced 1KB burst each.
// MODE 1: +bias, relu, A-fragment bf16 hi/lo out.
// MODE 3: f32 row-major out, each row scaled by rowscale[row] (dinv pre-scale).
template <int MODE>
__global__ __launch_bounds__(256) void gemm_frag(
    const unsigned short* __restrict__ Ahi, const unsigned short* __restrict__ Alo,
    const unsigned short* __restrict__ Bhi, const unsigned short* __restrict__ Blo,
    int M, const float* __restrict__ bias, float* __restrict__ outf,
    unsigned short* __restrict__ outhi, unsigned short* __restrict__ outlo,
    const float* __restrict__ rowscale) {
  int wid = threadIdx.x >> 6, lane = threadIdx.x & 63;
  int wm = wid & 1, wn = wid >> 1;
  int Mtiles = (M + 15) >> 4;
  int mt_base = blockIdx.x * 4 + wm * 2;
  int nt_base = blockIdx.y * 8 + wn * 4;
  int la8 = lane * 8;

  int mt0 = mt_base < Mtiles ? mt_base : Mtiles - 1;
  int mt1 = mt_base + 1 < Mtiles ? mt_base + 1 : Mtiles - 1;
  const unsigned short* a0h = Ahi + mt0 * 4096 + la8;
  const unsigned short* a0l = Alo + mt0 * 4096 + la8;
  const unsigned short* a1h = Ahi + mt1 * 4096 + la8;
  const unsigned short* a1l = Alo + mt1 * 4096 + la8;
  const unsigned short* bh = Bhi + nt_base * 4096 + la8;
  const unsigned short* bl = Blo + nt_base * 4096 + la8;

  f32x4 acc[2][4] = {};
#pragma unroll
  for (int k0 = 0; k0 < 8; ++k0) {
    bf16x8 A0h = *(const bf16x8*)(a0h + k0 * 512);
    bf16x8 A0l = *(const bf16x8*)(a0l + k0 * 512);
    bf16x8 A1h = *(const bf16x8*)(a1h + k0 * 512);
    bf16x8 A1l = *(const bf16x8*)(a1l + k0 * 512);
#pragma unroll
    for (int ni = 0; ni < 4; ++ni) {
      bf16x8 Bh = *(const bf16x8*)(bh + ni * 4096 + k0 * 512);
      bf16x8 Bl = *(const bf16x8*)(bl + ni * 4096 + k0 * 512);
      acc[0][ni] = __builtin_amdgcn_mfma_f32_16x16x32_bf16(A0h, Bh, acc[0][ni], 0, 0, 0);
      acc[0][ni] = __builtin_amdgcn_mfma_f32_16x16x32_bf16(A0h, Bl, acc[0][ni], 0, 0, 0);
      acc[0][ni] = __builtin_amdgcn_mfma_f32_16x16x32_bf16(A0l, Bh, acc[0][ni], 0, 0, 0);
      acc[1][ni] = __builtin_amdgcn_mfma_f32_16x16x32_bf16(A1h, Bh, acc[1][ni], 0, 0, 0);
      acc[1][ni] = __builtin_amdgcn_mfma_f32_16x16x32_bf16(A1h, Bl, acc[1][ni], 0, 0, 0);
      acc[1][ni] = __builtin_amdgcn_mfma_f32_16x16x32_bf16(A1l, Bh, acc[1][ni], 0, 0, 0);
    }
  }

  int r = lane & 15, g = lane >> 4;
#pragma unroll
  for (int mi = 0; mi < 2; ++mi) {
#pragma unroll
    for (int ii = 0; ii < 4; ++ii) {
      int row = (mt_base + mi) * 16 + g * 4 + ii;
      if (row >= M) continue;
      float rs = (MODE == 3) ? rowscale[row] : 1.0f;
#pragma unroll
      for (int ni = 0; ni < 4; ++ni) {
        int col = (nt_base + ni) * 16 + r;
        float v = acc[mi][ni][ii];
        if (MODE == 1) {
          v = fmaxf(v + bias[col], 0.0f);
          unsigned short h = f32_to_bf16(v);
          int addr = frag_addr(row, col);
          outhi[addr] = h;
          outlo[addr] = f32_to_bf16(v - bf16_to_f32(h));
        } else {
          outf[row * 256 + col] = v * rs;
        }
      }
    }
  }
}

// conv1 fused: t'[i] = dinv[i] * ( h1[i] @ w2wc ),
//   h1[i] = dinv[i]*(sum_{e in CSR(i)} g'[src] + g'[i]) + b1,  g' = dinv-scaled g1.
// One wave per node; lane owns cols [4*lane,4*lane+4).
// R10: x8-unrolled gather — 8 independent chains / outstanding 128B gathers.
__global__ __launch_bounds__(256) void gcn_conv_fused(
    const float* __restrict__ g, const int* __restrict__ row_ptr,
    const int* __restrict__ csr_src, const float* __restrict__ dinv,
    const float* __restrict__ b1, const float* __restrict__ w2wc,
    int n_nodes, float4* __restrict__ t4) {
  int wid = threadIdx.x >> 6, lane = threadIdx.x & 63;
  int node = blockIdx.x * 4 + wid;
  if (node >= n_nodes) return;
  const float4* hp = (const float4*)g;
  float4 a[8];
#pragma unroll
  for (int u = 0; u < 8; ++u) a[u] = make_float4(0.f, 0.f, 0.f, 0.f);
  int e0 = row_ptr[node], e1 = row_ptr[node + 1];
  int e = e0;
  for (; e + 7 < e1; e += 8) {
    int s[8];
#pragma unroll
    for (int u = 0; u < 8; ++u) s[u] = csr_src[e + u];
#pragma unroll
    for (int u = 0; u < 8; ++u) {
      float4 v = hp[s[u] * 64 + lane];
      a[u].x += v.x; a[u].y += v.y; a[u].z += v.z; a[u].w += v.w;
    }
  }
  for (; e + 3 < e1; e += 4) {
    int s[4];
#pragma unroll
    for (int u = 0; u < 4; ++u) s[u] = csr_src[e + u];
#pragma unroll
    for (int u = 0; u < 4; ++u) {
      float4 v = hp[s[u] * 64 + lane];
      a[u].x += v.x; a[u].y += v.y; a[u].z += v.z; a[u].w += v.w;
    }
  }
  for (; e < e1; ++e) {
    float4 v = hp[csr_src[e] * 64 + lane];
    a[0].x += v.x; a[0].y += v.y; a[0].z += v.z; a[0].w += v.w;
  }
  // tree-sum the 8 accumulators
#pragma unroll
  for (int u = 0; u < 4; ++u) {
    a[u].x += a[u + 4].x; a[u].y += a[u + 4].y;
    a[u].z += a[u + 4].z; a[u].w += a[u + 4].w;
  }
  a[0].x += a[2].x; a[0].y += a[2].y; a[0].z += a[2].z; a[0].w += a[2].w;
  a[1].x += a[3].x; a[1].y += a[3].y; a[1].z += a[3].z; a[1].w += a[3].w;
  a[0].x += a[1].x; a[0].y += a[1].y; a[0].z += a[1].z; a[0].w += a[1].w;

  float4 self = hp[node * 64 + lane];      // g'[node] = dinv[node]*g1[node]
  float di = dinv[node];
  float4 b4 = ((const float4*)b1)[lane];
  float o[4];
  o[0] = di * (a[0].x + self.x) + b4.x;
  o[1] = di * (a[0].y + self.y) + b4.y;
  o[2] = di * (a[0].z + self.z) + b4.z;
  o[3] = di * (a[0].w + self.w) + b4.w;
  // t = h1 @ w2wc (256x3), then pre-scale by di for conv2.
  float s0 = 0.f, s1 = 0.f, s2 = 0.f;
#pragma unroll
  for (int j = 0; j < 4; ++j) {
    int k = lane * 4 + j;
    s0 += o[j] * w2wc[k * 3 + 0];
    s1 += o[j] * w2wc[k * 3 + 1];
    s2 += o[j] * w2wc[k * 3 + 2];
  }
#pragma unroll
  for (int sh = 32; sh > 0; sh >>= 1) {
    s0 += __shfl_down(s0, sh);
    s1 += __shfl_down(s1, sh);
    s2 += __shfl_down(s2, sh);
  }
  if (lane == 0) t4[node] = make_float4(di * s0, di * s1, di * s2, 0.f);
}

// conv2 on 3 columns: logits[i] = dinv[i]*(sum t'[src] + t'[i]) + bvec.
// One thread per node; x2-unrolled 16B gathers (4MB total).
__global__ void conv2_skinny(const float4* __restrict__ t4,
                             const int* __restrict__ row_ptr,
                             const int* __restrict__ csr_src,
                             const float* __restrict__ dinv,
                             const float* __restrict__ bvec,
                             float* __restrict__ out, int n) {
  int i = blockIdx.x * blockDim.x + threadIdx.x;
  if (i >= n) return;
  int e = row_ptr[i], e1 = row_ptr[i + 1];
  float a0 = 0.f, a1 = 0.f, a2 = 0.f;
  float b0 = 0.f, b1 = 0.f, b2 = 0.f;
  for (; e + 1 < e1; e += 2) {
    float4 v0 = t4[csr_src[e]];
    float4 v1 = t4[csr_src[e + 1]];
    a0 += v0.x; a1 += v0.y; a2 += v0.z;
    b0 += v1.x; b1 += v1.y; b2 += v1.z;
  }
  if (e < e1) {
    float4 v0 = t4[csr_src[e]];
    a0 += v0.x; a1 += v0.y; a2 += v0.z;
  }
  float4 self = t4[i];
  float di = dinv[i];
  out[i * 3 + 0] = di * (a0 + b0 + self.x) + bvec[0];
  out[i * 3 + 1] = di * (a1 + b1 + self.y) + bvec[1];
  out[i * 3 + 2] = di * (a2 + b2 + self.z) + bvec[2];
}

extern "C" void kernel_launch(void* const* d_in, const int* in_sizes, int n_in,
                              void* d_out, int out_size, void* d_ws, size_t ws_size,
                              hipStream_t stream) {
  const float* x = (const float*)d_in[0];
  const int* ei = (const int*)d_in[1];
  const float* W_embed = (const float*)d_in[2];
  const float* b_embed = (const float*)d_in[3];
  const float* W1 = (const float*)d_in[4];
  const float* b1 = (const float*)d_in[5];
  const float* W2 = (const float*)d_in[6];
  const float* b2 = (const float*)d_in[7];
  const float* Wcls = (const float*)d_in[8];
  const float* bcls = (const float*)d_in[9];
  const int N = in_sizes[0] / 256;   // 20000
  const int E = in_sizes[1] / 2;     // 320000

  char* ws = (char*)d_ws;
  size_t off = 0;
  auto alloc = [&](size_t bytes) {
    void* p = ws + off;
    off = (off + bytes + 255) & ~(size_t)255;
    return p;
  };
  int* cnt = (int*)alloc((size_t)N * 4);
  int* cursor = (int*)alloc((size_t)N * 4);
  int* row_ptr = (int*)alloc((size_t)(N + 1) * 4);
  float* dinv = (float*)alloc((size_t)N * 4);
  int* csr_src = (int*)alloc((size_t)E * 4);
  int* flag = (int*)alloc(256);
  int* partials = (int*)alloc(4096);
  unsigned short* WemFhi = (unsigned short*)alloc(256 * 256 * 2);
  unsigned short* WemFlo = (unsigned short*)alloc(256 * 256 * 2);
  unsigned short* W1Fhi = (unsigned short*)alloc(256 * 256 * 2);
  unsigned short* W1Flo = (unsigned short*)alloc(256 * 256 * 2);
  float* w2wc = (float*)alloc(256 * 3 * 4);
  float* bvec = (float*)alloc(256);
  float4* t4 = (float4*)alloc((size_t)N * 16);
  size_t big = (size_t)N * 256;
  unsigned short* P1hi = (unsigned short*)alloc(big * 4);  // x frags (hi|lo)
  unsigned short* P1lo = P1hi + big;
  unsigned short* P2hi = (unsigned short*)alloc(big * 4);  // h0 frags (hi|lo)
  unsigned short* P2lo = P2hi + big;
  float* P3f = (float*)alloc(big * 4);                     // g1' f32

  int nb = (N + 255) / 256;  // 79 scan chunks
  int nz = (int)(((char*)row_ptr - (char*)cnt) / 4);  // cnt + cursor (incl pad)
  zero_ints<<<(nz + 255) / 256, 256, 0, stream>>>(cnt, nz);
  detect_i64<<<1, 256, 0, stream>>>((const unsigned int*)ei, 4096, flag);
  count_deg<<<(E + 255) / 256, 256, 0, stream>>>(ei, E, flag, cnt);
  scan_partials<<<nb, 256, 0, stream>>>(cnt, partials, N);
  scan_offsets<<<1, 1024, 0, stream>>>(partials, nb);
  scan_finalize<<<nb, 256, 0, stream>>>(cnt, partials, row_ptr, dinv, N);
  fill_csr<<<(E + 255) / 256, 256, 0, stream>>>(ei, E, flag, row_ptr, cursor, csr_src);

  split_x_frag<<<(N * 32 + 255) / 256, 256, 0, stream>>>((const float4*)x, P1hi, P1lo, N);
  pack_w_frag<<<256, 256, 0, stream>>>(W_embed, WemFhi, WemFlo);
  pack_w_frag<<<256, 256, 0, stream>>>(W1, W1Fhi, W1Flo);
  build_w2wc<<<1, 256, 0, stream>>>(W2, Wcls, b2, bcls, w2wc, bvec);

  dim3 gg((N + 63) / 64, 2);  // 64 rows x 128 cols per block
  // h0 = relu(x@We + be)  -> P2 frags
  gemm_frag<1><<<gg, 256, 0, stream>>>(P1hi, P1lo, WemFhi, WemFlo, N, b_embed,
                                       nullptr, P2hi, P2lo, nullptr);
  // g1' = dinv-rowscaled (h0@W1) -> P3f f32
  gemm_frag<3><<<gg, 256, 0, stream>>>(P2hi, P2lo, W1Fhi, W1Flo, N, nullptr,
                                       P3f, nullptr, nullptr, dinv);
  // t' = dinv * ((S g1 + b1) @ W2Wc)  -> t4 [N,4]
  gcn_conv_fused<<<(N + 3) / 4, 256, 0, stream>>>(P3f, row_ptr, csr_src, dinv, b1,
                                                  w2wc, N, t4);
  // logits = dinv*(sum t' + t'self) + bvec -> d_out
  conv2_skinny<<<(N + 255) / 256, 256, 0, stream>>>(t4, row_ptr, csr_src, dinv,
                                                    bvec, (float*)d_out, N);
}

// Round 14
// 210.360 us; speedup vs baseline: 2.0633x; 1.1649x over previous
//
#include <hip/hip_runtime.h>
#include <stdint.h>

// GCN forward on MI355X.
// R14: FULL linear-tail collapse. Everything after GEMM1's relu is linear:
//   logits = S·(S·(h0@P)) + (S·1)·q + bvec,  P = W1@(W2@Wc), q = b1@(W2@Wc)
// => GEMM2 deleted, conv1's 256-wide gather (43.4us, L2-miss-bound) deleted,
//    h0 never stored: GEMM1 epilogue reduces u = h0@P [N,3] via shfl+atomics.
//    Tail = two 3-col skinny convs on L2-resident 320KB.
// R12: parallel 3-kernel scan (single-block scan was 46.5us latency trap).
// R2 lesson: frag-major storage -> every GEMM load = 1KB coalesced burst.
// R13 counters: conv1 dur ~= FETCH(139MB)/3.3TB/s => L2-miss-traffic-bound;
//   harness d_ws 0xAA poison = 2x43.5us, not controllable.

typedef __attribute__((ext_vector_type(8))) __bf16 bf16x8;
typedef __attribute__((ext_vector_type(4))) float f32x4;

static __device__ __forceinline__ unsigned short f32_to_bf16(float f) {
  uint32_t u = __float_as_uint(f);
  u += 0x7fffu + ((u >> 16) & 1u);   // RNE (finite data)
  return (unsigned short)(u >> 16);
}
static __device__ __forceinline__ float bf16_to_f32(unsigned short h) {
  return __uint_as_float(((uint32_t)h) << 16);
}
static __device__ __forceinline__ int frag_addr(int m, int k) {
  return (((m >> 4) * 8 + (k >> 5)) << 9) + (((m & 15) + 16 * ((k >> 3) & 3)) << 3) + (k & 7);
}

__global__ void zero_ints(int* __restrict__ p, int n) {
  int i = blockIdx.x * blockDim.x + threadIdx.x;
  if (i < n) p[i] = 0;
}

// edge_index may arrive as int32 or int64; detect on-device (values < 2^31,
// so an int64 array has every odd dword == 0 little-endian).
__global__ void detect_i64(const unsigned int* __restrict__ ei, int nwords,
                           int* __restrict__ flag) {
  __shared__ int any;
  if (threadIdx.x == 0) any = 0;
  __syncthreads();
  for (int i = 1 + 2 * (int)threadIdx.x; i < nwords; i += 2 * blockDim.x)
    if (ei[i] != 0u) any = 1;
  __syncthreads();
  if (threadIdx.x == 0) *flag = (any == 0) ? 1 : 0;
}

__global__ void count_deg(const int* __restrict__ ei, int E,
                          const int* __restrict__ flag, int* __restrict__ cnt) {
  int e = blockIdx.x * blockDim.x + threadIdx.x;
  int is64 = *flag;
  if (e < E) {
    int d = is64 ? ei[2 * (E + e)] : ei[E + e];
    atomicAdd(&cnt[d], 1);
  }
}

// --- parallel scan: block sums -> scan partials -> finalize ---
__global__ __launch_bounds__(256) void scan_partials(
    const int* __restrict__ cnt, int* __restrict__ partials, int n) {
  __shared__ int sdata[256];
  int i = blockIdx.x * 256 + threadIdx.x;
  sdata[threadIdx.x] = (i < n) ? cnt[i] : 0;
  __syncthreads();
  for (int off = 128; off > 0; off >>= 1) {
    if (threadIdx.x < off) sdata[threadIdx.x] += sdata[threadIdx.x + off];
    __syncthreads();
  }
  if (threadIdx.x == 0) partials[blockIdx.x] = sdata[0];
}

__global__ __launch_bounds__(1024) void scan_offsets(int* __restrict__ partials,
                                                     int nb) {
  __shared__ int sdata[1024];
  int tid = threadIdx.x;
  sdata[tid] = (tid < nb) ? partials[tid] : 0;
  __syncthreads();
  for (int off = 1; off < 1024; off <<= 1) {
    int t = (tid >= off) ? sdata[tid - off] : 0;
    __syncthreads();
    sdata[tid] += t;
    __syncthreads();
  }
  if (tid < nb) partials[tid] = sdata[tid];
}

__global__ __launch_bounds__(256) void scan_finalize(
    const int* __restrict__ cnt, const int* __restrict__ partials_inc,
    int* __restrict__ row_ptr, float* __restrict__ dinv, int n) {
  __shared__ int sdata[256];
  int b = blockIdx.x;
  int i = b * 256 + threadIdx.x;
  int v = (i < n) ? cnt[i] : 0;
  sdata[threadIdx.x] = v;
  __syncthreads();
  for (int off = 1; off < 256; off <<= 1) {
    int t = (threadIdx.x >= off) ? sdata[threadIdx.x - off] : 0;
    __syncthreads();
    sdata[threadIdx.x] += t;
    __syncthreads();
  }
  int incl = sdata[threadIdx.x];
  int base = (b > 0) ? partials_inc[b - 1] : 0;
  if (i < n) {
    row_ptr[i] = base + incl - v;                // exclusive prefix
    dinv[i] = 1.0f / sqrtf((float)(v + 1));      // +1 self-loop
    if (i == n - 1) row_ptr[n] = base + incl;    // total
  }
}

__global__ void fill_csr(const int* __restrict__ ei, int E,
                         const int* __restrict__ flag,
                         const int* __restrict__ row_ptr, int* __restrict__ cursor,
                         int* __restrict__ csr_src) {
  int e = blockIdx.x * blockDim.x + threadIdx.x;
  int is64 = *flag;
  if (e < E) {
    int s = is64 ? ei[2 * e] : ei[e];
    int d = is64 ? ei[2 * (E + e)] : ei[E + e];
    int pos = row_ptr[d] + atomicAdd(&cursor[d], 1);
    csr_src[pos] = s;
  }
}

// x f32 row-major -> A-fragment-major bf16 hi/lo.
__global__ void split_x_frag(const float4* __restrict__ in,
                             unsigned short* __restrict__ hi,
                             unsigned short* __restrict__ lo, int M) {
  int t = blockIdx.x * blockDim.x + threadIdx.x;
  if (t >= M * 32) return;
  int m = t >> 5, o = t & 31;              // o = k-octet
  float4 v0 = in[m * 64 + o * 2];
  float4 v1 = in[m * 64 + o * 2 + 1];
  float f[8] = {v0.x, v0.y, v0.z, v0.w, v1.x, v1.y, v1.z, v1.w};
  unsigned short hs[8], ls[8];
#pragma unroll
  for (int j = 0; j < 8; ++j) {
    unsigned short h = f32_to_bf16(f[j]);
    hs[j] = h;
    ls[j] = f32_to_bf16(f[j] - bf16_to_f32(h));
  }
  int addr = frag_addr(m, o * 8);
  *(ushort4*)(hi + addr) = make_ushort4(hs[0], hs[1], hs[2], hs[3]);
  *(ushort4*)(hi + addr + 4) = make_ushort4(hs[4], hs[5], hs[6], hs[7]);
  *(ushort4*)(lo + addr) = make_ushort4(ls[0], ls[1], ls[2], ls[3]);
  *(ushort4*)(lo + addr + 4) = make_ushort4(ls[4], ls[5], ls[6], ls[7]);
}

// W [k][n] row-major 256x256 -> B-fragment-major bf16 hi/lo.
__global__ void pack_w_frag(const float* __restrict__ W,
                            unsigned short* __restrict__ hi,
                            unsigned short* __restrict__ lo) {
  int k = blockIdx.x, n = threadIdx.x;
  float v = W[k * 256 + n];
  unsigned short h = f32_to_bf16(v);
  int addr = frag_addr(n, k);  // B-frag: same formula with n as row
  hi[addr] = h;
  lo[addr] = f32_to_bf16(v - bf16_to_f32(h));
}

// P = W1@(W2@Wc) [256x3], q = b1@(W2@Wc) [3], bvec = b2@Wc + bc [3].
// One block, 256 threads, w2wc staged in LDS between phases.
__global__ __launch_bounds__(256) void build_tail(
    const float* __restrict__ W1, const float* __restrict__ b1,
    const float* __restrict__ W2, const float* __restrict__ Wc,
    const float* __restrict__ b2, const float* __restrict__ bc,
    float* __restrict__ P, float* __restrict__ q, float* __restrict__ bvec) {
  __shared__ float sw[256][3];
  int k = threadIdx.x;
  float s0 = 0.f, s1 = 0.f, s2 = 0.f;
  for (int n = 0; n < 256; ++n) {
    float w = W2[k * 256 + n];
    s0 += w * Wc[n * 3 + 0];
    s1 += w * Wc[n * 3 + 1];
    s2 += w * Wc[n * 3 + 2];
  }
  sw[k][0] = s0; sw[k][1] = s1; sw[k][2] = s2;
  __syncthreads();
  float p0 = 0.f, p1 = 0.f, p2 = 0.f;
  for (int n = 0; n < 256; ++n) {
    float w = W1[k * 256 + n];
    p0 += w * sw[n][0];
    p1 += w * sw[n][1];
    p2 += w * sw[n][2];
  }
  P[k * 3 + 0] = p0; P[k * 3 + 1] = p1; P[k * 3 + 2] = p2;
  if (k < 3) {
    float sq = 0.f, sb = 0.f;
    for (int n = 0; n < 256; ++n) {
      sq += b1[n] * sw[n][k];
      sb += b2[n] * Wc[n * 3 + k];
    }
    q[k] = sq;
    bvec[k] = sb + bc[k];
  }
}

// GEMM1 + fused u-reduction: u[row] += relu(x@We + be)[row] @ P  (atomics).
// Fragment-major A (x) and B (We), 3-term bf16 split MFMA, f32 accum.
// Block: 4 waves (2wm x 2wn), tile 64m x 128n; grid.y = 2 covers 256 cols.
// Epilogue: per-thread 4-col dot with P -> shfl-reduce over 16 r-lanes ->
// lane r==0 atomicAdds 8 rows x 3 (384 atomics/block, 240K total). h0 is
// NEVER materialized (saves the 40MB scattered 2B epilogue of old MODE 1).
__global__ __launch_bounds__(256) void gemm_u(
    const unsigned short* __restrict__ Ahi, const unsigned short* __restrict__ Alo,
    const unsigned short* __restrict__ Bhi, const unsigned short* __restrict__ Blo,
    int M, const float* __restrict__ bias, const float* __restrict__ P,
    float* __restrict__ u) {
  int wid = threadIdx.x >> 6, lane = threadIdx.x & 63;
  int wm = wid & 1, wn = wid >> 1;
  int Mtiles = (M + 15) >> 4;
  int mt_base = blockIdx.x * 4 + wm * 2;
  int nt_base = blockIdx.y * 8 + wn * 4;
  int la8 = lane * 8;

  int mt0 = mt_base < Mtiles ? mt_base : Mtiles - 1;
  int mt1 = mt_base + 1 < Mtiles ? mt_base + 1 : Mtiles - 1;
  const unsigned short* a0h = Ahi + mt0 * 4096 + la8;
  const unsigned short* a0l = Alo + mt0 * 4096 + la8;
  const unsigned short* a1h = Ahi + mt1 * 4096 + la8;
  const unsigned short* a1l = Alo + mt1 * 4096 + la8;
  const unsigned short* bh = Bhi + nt_base * 4096 + la8;
  const unsigned short* bl = Blo + nt_base * 4096 + la8;

  f32x4 acc[2][4] = {};
#pragma unroll
  for (int k0 = 0; k0 < 8; ++k0) {
    bf16x8 A0h = *(const bf16x8*)(a0h + k0 * 512);
    bf16x8 A0l = *(const bf16x8*)(a0l + k0 * 512);
    bf16x8 A1h = *(const bf16x8*)(a1h + k0 * 512);
    bf16x8 A1l = *(const bf16x8*)(a1l + k0 * 512);
#pragma unroll
    for (int ni = 0; ni < 4; ++ni) {
      bf16x8 Bh = *(const bf16x8*)(bh + ni * 4096 + k0 * 512);
      bf16x8 Bl = *(const bf16x8*)(bl + ni * 4096 + k0 * 512);
      acc[0][ni] = __builtin_amdgcn_mfma_f32_16x16x32_bf16(A0h, Bh, acc[0][ni], 0, 0, 0);
      acc[0][ni] = __builtin_amdgcn_mfma_f32_16x16x32_bf16(A0h, Bl, acc[0][ni], 0, 0, 0);
      acc[0][ni] = __builtin_amdgcn_mfma_f32_16x16x32_bf16(A0l, Bh, acc[0][ni], 0, 0, 0);
      acc[1][ni] = __builtin_amdgcn_mfma_f32_16x16x32_bf16(A1h, Bh, acc[1][ni], 0, 0, 0);
      acc[1][ni] = __builtin_amdgcn_mfma_f32_16x16x32_bf16(A1h, Bl, acc[1][ni], 0, 0, 0);
      acc[1][ni] = __builtin_amdgcn_mfma_f32_16x16x32_bf16(A1l, Bh, acc[1][ni], 0, 0, 0);
    }
  }

  int r = lane & 15, g = lane >> 4;
  float rp[8][3];
#pragma unroll
  for (int t = 0; t < 8; ++t) { rp[t][0] = 0.f; rp[t][1] = 0.f; rp[t][2] = 0.f; }
#pragma unroll
  for (int mi = 0; mi < 2; ++mi) {
#pragma unroll
    for (int ii = 0; ii < 4; ++ii) {
      int ri = mi * 4 + ii;
#pragma unroll
      for (int ni = 0; ni < 4; ++ni) {
        int col = (nt_base + ni) * 16 + r;
        float v = fmaxf(acc[mi][ni][ii] + bias[col], 0.0f);
        rp[ri][0] += v * P[col * 3 + 0];
        rp[ri][1] += v * P[col * 3 + 1];
        rp[ri][2] += v * P[col * 3 + 2];
      }
    }
  }
  // reduce over the 16 r-lanes (rows are shared across r, cols differ)
#pragma unroll
  for (int t = 0; t < 8; ++t) {
#pragma unroll
    for (int c = 0; c < 3; ++c) {
      float v = rp[t][c];
      v += __shfl_down(v, 8, 16);
      v += __shfl_down(v, 4, 16);
      v += __shfl_down(v, 2, 16);
      v += __shfl_down(v, 1, 16);
      rp[t][c] = v;
    }
  }
  if (r == 0) {
#pragma unroll
    for (int mi = 0; mi < 2; ++mi) {
#pragma unroll
      for (int ii = 0; ii < 4; ++ii) {
        int row = (mt_base + mi) * 16 + g * 4 + ii;
        if (row < M) {
          int ri = mi * 4 + ii;
          atomicAdd(&u[row * 3 + 0], rp[ri][0]);
          atomicAdd(&u[row * 3 + 1], rp[ri][1]);
          atomicAdd(&u[row * 3 + 2], rp[ri][2]);
        }
      }
    }
  }
}

// t4a[i] = (dinv_i*u[i], dinv_i)
__global__ void build_t4a(const float* __restrict__ u, const float* __restrict__ dinv,
                          float4* __restrict__ t4a, int n) {
  int i = blockIdx.x * blockDim.x + threadIdx.x;
  if (i >= n) return;
  float d = dinv[i];
  t4a[i] = make_float4(d * u[i * 3 + 0], d * u[i * 3 + 1], d * u[i * 3 + 2], d);
}

// passA: s = sum t4a[src] + t4a[i];  v_i = dinv_i*s.xyz (= S.(h0@P));
//        r_i = dinv_i*s.w (= (S.1)_i);  t4b[i] = (dinv_i*v_i, r_i).
__global__ void conv_skinnyA(const float4* __restrict__ t4a,
                             const int* __restrict__ row_ptr,
                             const int* __restrict__ csr_src,
                             const float* __restrict__ dinv,
                             float4* __restrict__ t4b, int n) {
  int i = blockIdx.x * blockDim.x + threadIdx.x;
  if (i >= n) return;
  int e = row_ptr[i], e1 = row_ptr[i + 1];
  float a0 = 0.f, a1 = 0.f, a2 = 0.f, a3 = 0.f;
  float b0 = 0.f, b1 = 0.f, b2 = 0.f, b3 = 0.f;
  for (; e + 1 < e1; e += 2) {
    float4 v0 = t4a[csr_src[e]];
    float4 v1 = t4a[csr_src[e + 1]];
    a0 += v0.x; a1 += v0.y; a2 += v0.z; a3 += v0.w;
    b0 += v1.x; b1 += v1.y; b2 += v1.z; b3 += v1.w;
  }
  if (e < e1) {
    float4 v0 = t4a[csr_src[e]];
    a0 += v0.x; a1 += v0.y; a2 += v0.z; a3 += v0.w;
  }
  float4 self = t4a[i];
  float d = dinv[i];
  float d2 = d * d;
  t4b[i] = make_float4(d2 * (a0 + b0 + self.x), d2 * (a1 + b1 + self.y),
                       d2 * (a2 + b2 + self.z), d * (a3 + b3 + self.w));
}

// passB: logits_i = dinv_i*(sum t4b[src].xyz + t4b[i].xyz) + q*r_i + bvec.
__global__ void conv_skinnyB(const float4* __restrict__ t4b,
                             const int* __restrict__ row_ptr,
                             const int* __restrict__ csr_src,
                             const float* __restrict__ dinv,
                             const float* __restrict__ q,
                             const float* __restrict__ bvec,
                             float* __restrict__ out, int n) {
  int i = blockIdx.x * blockDim.x + threadIdx.x;
  if (i >= n) return;
  int e = row_ptr[i], e1 = row_ptr[i + 1];
  float a0 = 0.f, a1 = 0.f, a2 = 0.f;
  float b0 = 0.f, b1 = 0.f, b2 = 0.f;
  for (; e + 1 < e1; e += 2) {
    float4 v0 = t4b[csr_src[e]];
    float4 v1 = t4b[csr_src[e + 1]];
    a0 += v0.x; a1 += v0.y; a2 += v0.z;
    b0 += v1.x; b1 += v1.y; b2 += v1.z;
  }
  if (e < e1) {
    float4 v0 = t4b[csr_src[e]];
    a0 += v0.x; a1 += v0.y; a2 += v0.z;
  }
  float4 self = t4b[i];
  float d = dinv[i];
  float r = self.w;
  out[i * 3 + 0] = d * (a0 + b0 + self.x) + q[0] * r + bvec[0];
  out[i * 3 + 1] = d * (a1 + b1 + self.y) + q[1] * r + bvec[1];
  out[i * 3 + 2] = d * (a2 + b2 + self.z) + q[2] * r + bvec[2];
}

extern "C" void kernel_launch(void* const* d_in, const int* in_sizes, int n_in,
                              void* d_out, int out_size, void* d_ws, size_t ws_size,
                              hipStream_t stream) {
  const float* x = (const float*)d_in[0];
  const int* ei = (const int*)d_in[1];
  const float* W_embed = (const float*)d_in[2];
  const float* b_embed = (const float*)d_in[3];
  const float* W1 = (const float*)d_in[4];
  const float* b1 = (const float*)d_in[5];
  const float* W2 = (const float*)d_in[6];
  const float* b2 = (const float*)d_in[7];
  const float* Wcls = (const float*)d_in[8];
  const float* bcls = (const float*)d_in[9];
  const int N = in_sizes[0] / 256;   // 20000
  const int E = in_sizes[1] / 2;     // 320000

  char* ws = (char*)d_ws;
  size_t off = 0;
  auto alloc = [&](size_t bytes) {
    void* p = ws + off;
    off = (off + bytes + 255) & ~(size_t)255;
    return p;
  };
  int* cnt = (int*)alloc((size_t)N * 4);
  int* cursor = (int*)alloc((size_t)N * 4);
  int* row_ptr = (int*)alloc((size_t)(N + 1) * 4);
  float* dinv = (float*)alloc((size_t)N * 4);
  int* csr_src = (int*)alloc((size_t)E * 4);
  int* flag = (int*)alloc(256);
  int* partials = (int*)alloc(4096);
  unsigned short* WemFhi = (unsigned short*)alloc(256 * 256 * 2);
  unsigned short* WemFlo = (unsigned short*)alloc(256 * 256 * 2);
  float* P = (float*)alloc(256 * 3 * 4);
  float* q = (float*)alloc(256);
  float* bvec = (float*)alloc(256);
  float* u = (float*)alloc((size_t)N * 3 * 4);
  float4* t4a = (float4*)alloc((size_t)N * 16);
  float4* t4b = (float4*)alloc((size_t)N * 16);
  size_t big = (size_t)N * 256;
  unsigned short* P1hi = (unsigned short*)alloc(big * 4);  // x frags (hi|lo)
  unsigned short* P1lo = P1hi + big;

  int nb = (N + 255) / 256;  // scan chunks
  int nz = (int)(((char*)row_ptr - (char*)cnt) / 4);  // cnt + cursor (incl pad)
  zero_ints<<<(nz + 255) / 256, 256, 0, stream>>>(cnt, nz);
  zero_ints<<<(N * 3 + 255) / 256, 256, 0, stream>>>((int*)u, N * 3);
  detect_i64<<<1, 256, 0, stream>>>((const unsigned int*)ei, 4096, flag);
  count_deg<<<(E + 255) / 256, 256, 0, stream>>>(ei, E, flag, cnt);
  scan_partials<<<nb, 256, 0, stream>>>(cnt, partials, N);
  scan_offsets<<<1, 1024, 0, stream>>>(partials, nb);
  scan_finalize<<<nb, 256, 0, stream>>>(cnt, partials, row_ptr, dinv, N);
  fill_csr<<<(E + 255) / 256, 256, 0, stream>>>(ei, E, flag, row_ptr, cursor, csr_src);

  split_x_frag<<<(N * 32 + 255) / 256, 256, 0, stream>>>((const float4*)x, P1hi, P1lo, N);
  pack_w_frag<<<256, 256, 0, stream>>>(W_embed, WemFhi, WemFlo);
  build_tail<<<1, 256, 0, stream>>>(W1, b1, W2, Wcls, b2, bcls, P, q, bvec);

  dim3 gg((N + 63) / 64, 2);  // 64 rows x 128 cols per block
  // u = relu(x@We + be) @ P   (h0 never materialized)
  gemm_u<<<gg, 256, 0, stream>>>(P1hi, P1lo, WemFhi, WemFlo, N, b_embed, P, u);
  // t4a = (dinv*u, dinv)
  build_t4a<<<(N + 255) / 256, 256, 0, stream>>>(u, dinv, t4a, N);
  // passA: t4b = (dinv*(S.(h0@P)), S.1)
  conv_skinnyA<<<(N + 255) / 256, 256, 0, stream>>>(t4a, row_ptr, csr_src, dinv,
                                                    t4b, N);
  // passB: logits
  conv_skinnyB<<<(N + 255) / 256, 256, 0, stream>>>(t4b, row_ptr, csr_src, dinv,
                                                    q, bvec, (float*)d_out, N);
}

// Round 15
// 186.929 us; speedup vs baseline: 2.3219x; 1.1253x over previous
//
#include <hip/hip_runtime.h>
#include <stdint.h>

// GCN forward on MI355X.
// R14: FULL linear-tail collapse: logits = S·(S·(h0@P)) + (S·1)·q + bvec,
//   P = W1@(W2@Wc), q = b1@(W2@Wc). GEMM2 + conv1 (256-wide) deleted;
//   h0 never stored (GEMM1 epilogue reduces u = h0@P via shfl+atomics).
// R15: build_tail was a 1-block, serial-256-loop latency trap (~40us, hidden
//   just under the 44us poison fills) -> wave-per-row parallel matvec3.
// R12: parallel 3-kernel scan (single-block scan was the same trap, 46.5us).
// R2 lesson: frag-major storage -> every GEMM load = 1KB coalesced burst.
// R13/R14: top-5 = harness 0xAA d_ws poison (44us/fill), uncontrollable.

typedef __attribute__((ext_vector_type(8))) __bf16 bf16x8;
typedef __attribute__((ext_vector_type(4))) float f32x4;

static __device__ __forceinline__ unsigned short f32_to_bf16(float f) {
  uint32_t u = __float_as_uint(f);
  u += 0x7fffu + ((u >> 16) & 1u);   // RNE (finite data)
  return (unsigned short)(u >> 16);
}
static __device__ __forceinline__ float bf16_to_f32(unsigned short h) {
  return __uint_as_float(((uint32_t)h) << 16);
}
static __device__ __forceinline__ int frag_addr(int m, int k) {
  return (((m >> 4) * 8 + (k >> 5)) << 9) + (((m & 15) + 16 * ((k >> 3) & 3)) << 3) + (k & 7);
}

__global__ void zero_ints(int* __restrict__ p, int n) {
  int i = blockIdx.x * blockDim.x + threadIdx.x;
  if (i < n) p[i] = 0;
}

// edge_index may arrive as int32 or int64; detect on-device (values < 2^31,
// so an int64 array has every odd dword == 0 little-endian).
__global__ void detect_i64(const unsigned int* __restrict__ ei, int nwords,
                           int* __restrict__ flag) {
  __shared__ int any;
  if (threadIdx.x == 0) any = 0;
  __syncthreads();
  for (int i = 1 + 2 * (int)threadIdx.x; i < nwords; i += 2 * blockDim.x)
    if (ei[i] != 0u) any = 1;
  __syncthreads();
  if (threadIdx.x == 0) *flag = (any == 0) ? 1 : 0;
}

__global__ void count_deg(const int* __restrict__ ei, int E,
                          const int* __restrict__ flag, int* __restrict__ cnt) {
  int e = blockIdx.x * blockDim.x + threadIdx.x;
  int is64 = *flag;
  if (e < E) {
    int d = is64 ? ei[2 * (E + e)] : ei[E + e];
    atomicAdd(&cnt[d], 1);
  }
}

// --- parallel scan: block sums -> scan partials -> finalize ---
__global__ __launch_bounds__(256) void scan_partials(
    const int* __restrict__ cnt, int* __restrict__ partials, int n) {
  __shared__ int sdata[256];
  int i = blockIdx.x * 256 + threadIdx.x;
  sdata[threadIdx.x] = (i < n) ? cnt[i] : 0;
  __syncthreads();
  for (int off = 128; off > 0; off >>= 1) {
    if (threadIdx.x < off) sdata[threadIdx.x] += sdata[threadIdx.x + off];
    __syncthreads();
  }
  if (threadIdx.x == 0) partials[blockIdx.x] = sdata[0];
}

__global__ __launch_bounds__(1024) void scan_offsets(int* __restrict__ partials,
                                                     int nb) {
  __shared__ int sdata[1024];
  int tid = threadIdx.x;
  sdata[tid] = (tid < nb) ? partials[tid] : 0;
  __syncthreads();
  for (int off = 1; off < 1024; off <<= 1) {
    int t = (tid >= off) ? sdata[tid - off] : 0;
    __syncthreads();
    sdata[tid] += t;
    __syncthreads();
  }
  if (tid < nb) partials[tid] = sdata[tid];
}

__global__ __launch_bounds__(256) void scan_finalize(
    const int* __restrict__ cnt, const int* __restrict__ partials_inc,
    int* __restrict__ row_ptr, float* __restrict__ dinv, int n) {
  __shared__ int sdata[256];
  int b = blockIdx.x;
  int i = b * 256 + threadIdx.x;
  int v = (i < n) ? cnt[i] : 0;
  sdata[threadIdx.x] = v;
  __syncthreads();
  for (int off = 1; off < 256; off <<= 1) {
    int t = (threadIdx.x >= off) ? sdata[threadIdx.x - off] : 0;
    __syncthreads();
    sdata[threadIdx.x] += t;
    __syncthreads();
  }
  int incl = sdata[threadIdx.x];
  int base = (b > 0) ? partials_inc[b - 1] : 0;
  if (i < n) {
    row_ptr[i] = base + incl - v;                // exclusive prefix
    dinv[i] = 1.0f / sqrtf((float)(v + 1));      // +1 self-loop
    if (i == n - 1) row_ptr[n] = base + incl;    // total
  }
}

__global__ void fill_csr(const int* __restrict__ ei, int E,
                         const int* __restrict__ flag,
                         const int* __restrict__ row_ptr, int* __restrict__ cursor,
                         int* __restrict__ csr_src) {
  int e = blockIdx.x * blockDim.x + threadIdx.x;
  int is64 = *flag;
  if (e < E) {
    int s = is64 ? ei[2 * e] : ei[e];
    int d = is64 ? ei[2 * (E + e)] : ei[E + e];
    int pos = row_ptr[d] + atomicAdd(&cursor[d], 1);
    csr_src[pos] = s;
  }
}

// x f32 row-major -> A-fragment-major bf16 hi/lo.
__global__ void split_x_frag(const float4* __restrict__ in,
                             unsigned short* __restrict__ hi,
                             unsigned short* __restrict__ lo, int M) {
  int t = blockIdx.x * blockDim.x + threadIdx.x;
  if (t >= M * 32) return;
  int m = t >> 5, o = t & 31;              // o = k-octet
  float4 v0 = in[m * 64 + o * 2];
  float4 v1 = in[m * 64 + o * 2 + 1];
  float f[8] = {v0.x, v0.y, v0.z, v0.w, v1.x, v1.y, v1.z, v1.w};
  unsigned short hs[8], ls[8];
#pragma unroll
  for (int j = 0; j < 8; ++j) {
    unsigned short h = f32_to_bf16(f[j]);
    hs[j] = h;
    ls[j] = f32_to_bf16(f[j] - bf16_to_f32(h));
  }
  int addr = frag_addr(m, o * 8);
  *(ushort4*)(hi + addr) = make_ushort4(hs[0], hs[1], hs[2], hs[3]);
  *(ushort4*)(hi + addr + 4) = make_ushort4(hs[4], hs[5], hs[6], hs[7]);
  *(ushort4*)(lo + addr) = make_ushort4(ls[0], ls[1], ls[2], ls[3]);
  *(ushort4*)(lo + addr + 4) = make_ushort4(ls[4], ls[5], ls[6], ls[7]);
}

// W [k][n] row-major 256x256 -> B-fragment-major bf16 hi/lo.
__global__ void pack_w_frag(const float* __restrict__ W,
                            unsigned short* __restrict__ hi,
                            unsigned short* __restrict__ lo) {
  int k = blockIdx.x, n = threadIdx.x;
  float v = W[k * 256 + n];
  unsigned short h = f32_to_bf16(v);
  int addr = frag_addr(n, k);  // B-frag: same formula with n as row
  hi[addr] = h;
  lo[addr] = f32_to_bf16(v - bf16_to_f32(h));
}

// O3 = A @ B3   (A [256,256] row-major, B3 [256,3]); one wave per row k.
// float4 coalesced row load + 3 shfl-reduce chains. 64 blocks x 4 waves.
__global__ __launch_bounds__(256) void tail_matvec3(
    const float* __restrict__ A, const float* __restrict__ B3,
    float* __restrict__ O3) {
  int wid = threadIdx.x >> 6, lane = threadIdx.x & 63;
  int k = blockIdx.x * 4 + wid;
  float4 a = ((const float4*)(A + k * 256))[lane];
  int n0 = lane * 4;
  float s0 = a.x * B3[n0 * 3 + 0] + a.y * B3[n0 * 3 + 3] +
             a.z * B3[n0 * 3 + 6] + a.w * B3[n0 * 3 + 9];
  float s1 = a.x * B3[n0 * 3 + 1] + a.y * B3[n0 * 3 + 4] +
             a.z * B3[n0 * 3 + 7] + a.w * B3[n0 * 3 + 10];
  float s2 = a.x * B3[n0 * 3 + 2] + a.y * B3[n0 * 3 + 5] +
             a.z * B3[n0 * 3 + 8] + a.w * B3[n0 * 3 + 11];
#pragma unroll
  for (int off = 32; off > 0; off >>= 1) {
    s0 += __shfl_down(s0, off);
    s1 += __shfl_down(s1, off);
    s2 += __shfl_down(s2, off);
  }
  if (lane == 0) {
    O3[k * 3 + 0] = s0;
    O3[k * 3 + 1] = s1;
    O3[k * 3 + 2] = s2;
  }
}

// q = b1 @ w2wc;  bvec = b2 @ Wc + bc.  Two waves, one vector each.
__global__ __launch_bounds__(128) void tail_vec(
    const float* __restrict__ b1, const float* __restrict__ w2wc,
    const float* __restrict__ b2, const float* __restrict__ Wc,
    const float* __restrict__ bc, float* __restrict__ q,
    float* __restrict__ bvec) {
  int wid = threadIdx.x >> 6, lane = threadIdx.x & 63;
  const float* vin = (wid == 0) ? b1 : b2;
  const float* mat = (wid == 0) ? w2wc : Wc;
  float4 a = ((const float4*)vin)[lane];
  int n0 = lane * 4;
  float s0 = a.x * mat[n0 * 3 + 0] + a.y * mat[n0 * 3 + 3] +
             a.z * mat[n0 * 3 + 6] + a.w * mat[n0 * 3 + 9];
  float s1 = a.x * mat[n0 * 3 + 1] + a.y * mat[n0 * 3 + 4] +
             a.z * mat[n0 * 3 + 7] + a.w * mat[n0 * 3 + 10];
  float s2 = a.x * mat[n0 * 3 + 2] + a.y * mat[n0 * 3 + 5] +
             a.z * mat[n0 * 3 + 8] + a.w * mat[n0 * 3 + 11];
#pragma unroll
  for (int off = 32; off > 0; off >>= 1) {
    s0 += __shfl_down(s0, off);
    s1 += __shfl_down(s1, off);
    s2 += __shfl_down(s2, off);
  }
  if (lane == 0) {
    if (wid == 0) {
      q[0] = s0; q[1] = s1; q[2] = s2;
    } else {
      bvec[0] = s0 + bc[0]; bvec[1] = s1 + bc[1]; bvec[2] = s2 + bc[2];
    }
  }
}

// GEMM1 + fused u-reduction: u[row] += relu(x@We + be)[row] @ P  (atomics).
// Fragment-major A (x) and B (We), 3-term bf16 split MFMA, f32 accum.
// Block: 4 waves (2wm x 2wn), tile 64m x 128n; grid.y = 2 covers 256 cols.
// Epilogue: per-thread 4-col dot with P -> shfl-reduce over 16 r-lanes ->
// lane r==0 atomicAdds 8 rows x 3 (384 atomics/block). h0 never stored.
__global__ __launch_bounds__(256) void gemm_u(
    const unsigned short* __restrict__ Ahi, const unsigned short* __restrict__ Alo,
    const unsigned short* __restrict__ Bhi, const unsigned short* __restrict__ Blo,
    int M, const float* __restrict__ bias, const float* __restrict__ P,
    float* __restrict__ u) {
  int wid = threadIdx.x >> 6, lane = threadIdx.x & 63;
  int wm = wid & 1, wn = wid >> 1;
  int Mtiles = (M + 15) >> 4;
  int mt_base = blockIdx.x * 4 + wm * 2;
  int nt_base = blockIdx.y * 8 + wn * 4;
  int la8 = lane * 8;

  int mt0 = mt_base < Mtiles ? mt_base : Mtiles - 1;
  int mt1 = mt_base + 1 < Mtiles ? mt_base + 1 : Mtiles - 1;
  const unsigned short* a0h = Ahi + mt0 * 4096 + la8;
  const unsigned short* a0l = Alo + mt0 * 4096 + la8;
  const unsigned short* a1h = Ahi + mt1 * 4096 + la8;
  const unsigned short* a1l = Alo + mt1 * 4096 + la8;
  const unsigned short* bh = Bhi + nt_base * 4096 + la8;
  const unsigned short* bl = Blo + nt_base * 4096 + la8;

  f32x4 acc[2][4] = {};
#pragma unroll
  for (int k0 = 0; k0 < 8; ++k0) {
    bf16x8 A0h = *(const bf16x8*)(a0h + k0 * 512);
    bf16x8 A0l = *(const bf16x8*)(a0l + k0 * 512);
    bf16x8 A1h = *(const bf16x8*)(a1h + k0 * 512);
    bf16x8 A1l = *(const bf16x8*)(a1l + k0 * 512);
#pragma unroll
    for (int ni = 0; ni < 4; ++ni) {
      bf16x8 Bh = *(const bf16x8*)(bh + ni * 4096 + k0 * 512);
      bf16x8 Bl = *(const bf16x8*)(bl + ni * 4096 + k0 * 512);
      acc[0][ni] = __builtin_amdgcn_mfma_f32_16x16x32_bf16(A0h, Bh, acc[0][ni], 0, 0, 0);
      acc[0][ni] = __builtin_amdgcn_mfma_f32_16x16x32_bf16(A0h, Bl, acc[0][ni], 0, 0, 0);
      acc[0][ni] = __builtin_amdgcn_mfma_f32_16x16x32_bf16(A0l, Bh, acc[0][ni], 0, 0, 0);
      acc[1][ni] = __builtin_amdgcn_mfma_f32_16x16x32_bf16(A1h, Bh, acc[1][ni], 0, 0, 0);
      acc[1][ni] = __builtin_amdgcn_mfma_f32_16x16x32_bf16(A1h, Bl, acc[1][ni], 0, 0, 0);
      acc[1][ni] = __builtin_amdgcn_mfma_f32_16x16x32_bf16(A1l, Bh, acc[1][ni], 0, 0, 0);
    }
  }

  int r = lane & 15, g = lane >> 4;
  float rp[8][3];
#pragma unroll
  for (int t = 0; t < 8; ++t) { rp[t][0] = 0.f; rp[t][1] = 0.f; rp[t][2] = 0.f; }
#pragma unroll
  for (int mi = 0; mi < 2; ++mi) {
#pragma unroll
    for (int ii = 0; ii < 4; ++ii) {
      int ri = mi * 4 + ii;
#pragma unroll
      for (int ni = 0; ni < 4; ++ni) {
        int col = (nt_base + ni) * 16 + r;
        float v = fmaxf(acc[mi][ni][ii] + bias[col], 0.0f);
        rp[ri][0] += v * P[col * 3 + 0];
        rp[ri][1] += v * P[col * 3 + 1];
        rp[ri][2] += v * P[col * 3 + 2];
      }
    }
  }
  // reduce over the 16 r-lanes (rows shared across r, cols differ)
#pragma unroll
  for (int t = 0; t < 8; ++t) {
#pragma unroll
    for (int c = 0; c < 3; ++c) {
      float v = rp[t][c];
      v += __shfl_down(v, 8, 16);
      v += __shfl_down(v, 4, 16);
      v += __shfl_down(v, 2, 16);
      v += __shfl_down(v, 1, 16);
      rp[t][c] = v;
    }
  }
  if (r == 0) {
#pragma unroll
    for (int mi = 0; mi < 2; ++mi) {
#pragma unroll
      for (int ii = 0; ii < 4; ++ii) {
        int row = (mt_base + mi) * 16 + g * 4 + ii;
        if (row < M) {
          int ri = mi * 4 + ii;
          atomicAdd(&u[row * 3 + 0], rp[ri][0]);
          atomicAdd(&u[row * 3 + 1], rp[ri][1]);
          atomicAdd(&u[row * 3 + 2], rp[ri][2]);
        }
      }
    }
  }
}

// t4a[i] = (dinv_i*u[i], dinv_i)
__global__ void build_t4a(const float* __restrict__ u, const float* __restrict__ dinv,
                          float4* __restrict__ t4a, int n) {
  int i = blockIdx.x * blockDim.x + threadIdx.x;
  if (i >= n) return;
  float d = dinv[i];
  t4a[i] = make_float4(d * u[i * 3 + 0], d * u[i * 3 + 1], d * u[i * 3 + 2], d);
}

// passA: s = sum t4a[src] + t4a[i];  t4b[i] = (dinv_i^2*s.xyz, dinv_i*s.w).
__global__ void conv_skinnyA(const float4* __restrict__ t4a,
                             const int* __restrict__ row_ptr,
                             const int* __restrict__ csr_src,
                             const float* __restrict__ dinv,
                             float4* __restrict__ t4b, int n) {
  int i = blockIdx.x * blockDim.x + threadIdx.x;
  if (i >= n) return;
  int e = row_ptr[i], e1 = row_ptr[i + 1];
  float a0 = 0.f, a1 = 0.f, a2 = 0.f, a3 = 0.f;
  float b0 = 0.f, b1 = 0.f, b2 = 0.f, b3 = 0.f;
  for (; e + 1 < e1; e += 2) {
    float4 v0 = t4a[csr_src[e]];
    float4 v1 = t4a[csr_src[e + 1]];
    a0 += v0.x; a1 += v0.y; a2 += v0.z; a3 += v0.w;
    b0 += v1.x; b1 += v1.y; b2 += v1.z; b3 += v1.w;
  }
  if (e < e1) {
    float4 v0 = t4a[csr_src[e]];
    a0 += v0.x; a1 += v0.y; a2 += v0.z; a3 += v0.w;
  }
  float4 self = t4a[i];
  float d = dinv[i];
  float d2 = d * d;
  t4b[i] = make_float4(d2 * (a0 + b0 + self.x), d2 * (a1 + b1 + self.y),
                       d2 * (a2 + b2 + self.z), d * (a3 + b3 + self.w));
}

// passB: logits_i = dinv_i*(sum t4b[src].xyz + t4b[i].xyz) + q*r_i + bvec.
__global__ void conv_skinnyB(const float4* __restrict__ t4b,
                             const int* __restrict__ row_ptr,
                             const int* __restrict__ csr_src,
                             const float* __restrict__ dinv,
                             const float* __restrict__ q,
                             const float* __restrict__ bvec,
                             float* __restrict__ out, int n) {
  int i = blockIdx.x * blockDim.x + threadIdx.x;
  if (i >= n) return;
  int e = row_ptr[i], e1 = row_ptr[i + 1];
  float a0 = 0.f, a1 = 0.f, a2 = 0.f;
  float b0 = 0.f, b1 = 0.f, b2 = 0.f;
  for (; e + 1 < e1; e += 2) {
    float4 v0 = t4b[csr_src[e]];
    float4 v1 = t4b[csr_src[e + 1]];
    a0 += v0.x; a1 += v0.y; a2 += v0.z;
    b0 += v1.x; b1 += v1.y; b2 += v1.z;
  }
  if (e < e1) {
    float4 v0 = t4b[csr_src[e]];
    a0 += v0.x; a1 += v0.y; a2 += v0.z;
  }
  float4 self = t4b[i];
  float d = dinv[i];
  float r = self.w;
  out[i * 3 + 0] = d * (a0 + b0 + self.x) + q[0] * r + bvec[0];
  out[i * 3 + 1] = d * (a1 + b1 + self.y) + q[1] * r + bvec[1];
  out[i * 3 + 2] = d * (a2 + b2 + self.z) + q[2] * r + bvec[2];
}

extern "C" void kernel_launch(void* const* d_in, const int* in_sizes, int n_in,
                              void* d_out, int out_size, void* d_ws, size_t ws_size,
                              hipStream_t stream) {
  const float* x = (const float*)d_in[0];
  const int* ei = (const int*)d_in[1];
  const float* W_embed = (const float*)d_in[2];
  const float* b_embed = (const float*)d_in[3];
  const float* W1 = (const float*)d_in[4];
  const float* b1 = (const float*)d_in[5];
  const float* W2 = (const float*)d_in[6];
  const float* b2 = (const float*)d_in[7];
  const float* Wcls = (const float*)d_in[8];
  const float* bcls = (const float*)d_in[9];
  const int N = in_sizes[0] / 256;   // 20000
  const int E = in_sizes[1] / 2;     // 320000

  char* ws = (char*)d_ws;
  size_t off = 0;
  auto alloc = [&](size_t bytes) {
    void* p = ws + off;
    off = (off + bytes + 255) & ~(size_t)255;
    return p;
  };
  int* cnt = (int*)alloc((size_t)N * 4);
  int* cursor = (int*)alloc((size_t)N * 4);
  int* row_ptr = (int*)alloc((size_t)(N + 1) * 4);
  float* dinv = (float*)alloc((size_t)N * 4);
  int* csr_src = (int*)alloc((size_t)E * 4);
  int* flag = (int*)alloc(256);
  int* partials = (int*)alloc(4096);
  unsigned short* WemFhi = (unsigned short*)alloc(256 * 256 * 2);
  unsigned short* WemFlo = (unsigned short*)alloc(256 * 256 * 2);
  float* w2wc = (float*)alloc(256 * 3 * 4);
  float* P = (float*)alloc(256 * 3 * 4);
  float* q = (float*)alloc(256);
  float* bvec = (float*)alloc(256);
  float* u = (float*)alloc((size_t)N * 3 * 4);
  float4* t4a = (float4*)alloc((size_t)N * 16);
  float4* t4b = (float4*)alloc((size_t)N * 16);
  size_t big = (size_t)N * 256;
  unsigned short* P1hi = (unsigned short*)alloc(big * 4);  // x frags (hi|lo)
  unsigned short* P1lo = P1hi + big;

  int nb = (N + 255) / 256;  // scan chunks
  int nz = (int)(((char*)row_ptr - (char*)cnt) / 4);  // cnt + cursor (incl pad)
  zero_ints<<<(nz + 255) / 256, 256, 0, stream>>>(cnt, nz);
  zero_ints<<<(N * 3 + 255) / 256, 256, 0, stream>>>((int*)u, N * 3);
  detect_i64<<<1, 256, 0, stream>>>((const unsigned int*)ei, 4096, flag);
  count_deg<<<(E + 255) / 256, 256, 0, stream>>>(ei, E, flag, cnt);
  scan_partials<<<nb, 256, 0, stream>>>(cnt, partials, N);
  scan_offsets<<<1, 1024, 0, stream>>>(partials, nb);
  scan_finalize<<<nb, 256, 0, stream>>>(cnt, partials, row_ptr, dinv, N);
  fill_csr<<<(E + 255) / 256, 256, 0, stream>>>(ei, E, flag, row_ptr, cursor, csr_src);

  split_x_frag<<<(N * 32 + 255) / 256, 256, 0, stream>>>((const float4*)x, P1hi, P1lo, N);
  pack_w_frag<<<256, 256, 0, stream>>>(W_embed, WemFhi, WemFlo);
  // tail weights: w2wc = W2@Wc;  P = W1@w2wc;  q = b1@w2wc;  bvec = b2@Wc + bc
  tail_matvec3<<<64, 256, 0, stream>>>(W2, Wcls, w2wc);
  tail_matvec3<<<64, 256, 0, stream>>>(W1, w2wc, P);
  tail_vec<<<1, 128, 0, stream>>>(b1, w2wc, b2, Wcls, bcls, q, bvec);

  dim3 gg((N + 63) / 64, 2);  // 64 rows x 128 cols per block
  // u = relu(x@We + be) @ P   (h0 never materialized)
  gemm_u<<<gg, 256, 0, stream>>>(P1hi, P1lo, WemFhi, WemFlo, N, b_embed, P, u);
  // t4a = (dinv*u, dinv)
  build_t4a<<<(N + 255) / 256, 256, 0, stream>>>(u, dinv, t4a, N);
  // passA: t4b = (dinv*(S.(h0@P)), S.1)
  conv_skinnyA<<<(N + 255) / 256, 256, 0, stream>>>(t4a, row_ptr, csr_src, dinv,
                                                    t4b, N);
  // passB: logits
  conv_skinnyB<<<(N + 255) / 256, 256, 0, stream>>>(t4b, row_ptr, csr_src, dinv,
                                                    q, bvec, (float*)d_out, N);
}